// Round 4
// baseline (3881.801 us; speedup 1.0000x reference)
//
#include <hip/hip_runtime.h>
#include <hip/hip_bf16.h>

#define NATOMS 16384
#define MOLS   64
#define ATOMSM 256
#define EGB    524288
#define EGNN   262144
#define HID    128
#define NH     (NATOMS*HID)

#define OFFSETC 0.009f
#define ALPHAC  1.0f
#define BETAC   0.8f
#define GAMMAC  4.85f
#define PREFC   (-138.935456f*(1.0f-1.0f/78.5f))

__device__ __forceinline__ float sigf(float x){ return 1.0f/(1.0f+__expf(-x)); }
__device__ __forceinline__ float waveRed(float v){
    v += __shfl_xor(v,32); v += __shfl_xor(v,16); v += __shfl_xor(v,8);
    v += __shfl_xor(v,4);  v += __shfl_xor(v,2);  v += __shfl_xor(v,1);
    return v;
}

// ============ fused GB chain: one block per molecule, all state in LDS ============
__global__ __launch_bounds__(512) void k_gb(
    const float* __restrict__ pos, const float* __restrict__ feat,
    const int* __restrict__ ei, float* __restrict__ grad, float* __restrict__ egbM)
{
    __shared__ float sPx[256], sPy[256], sPz[256];
    __shared__ float sQ[256], sSr[256], sRho[256], sRad[256];
    __shared__ float sI[256], sB[256], scB[256], sgB[256], sE[256];
    __shared__ float sGx[256], sGy[256], sGz[256];
    __shared__ float red[4];
    const int m = blockIdx.x, tid = threadIdx.x;
    const int abase = 256*m;
    if (tid < 256){
        int i = abase + tid;
        sPx[tid]=pos[3*i]; sPy[tid]=pos[3*i+1]; sPz[tid]=pos[3*i+2];
        float q = feat[7*i], rad = feat[7*i+1], sc = feat[7*i+2];
        sQ[tid]=q; sRad[tid]=rad;
        float rho = rad-OFFSETC; sRho[tid]=rho; sSr[tid]=sc*rho;
        sI[tid]=0.f; sE[tid]=0.f;
        sGx[tid]=0.f; sGy[tid]=0.f; sGz[tid]=0.f;
    }
    __syncthreads();
    const int* dP = ei + EGB + 8192*m;
    const int e0 = tid*16;        // 16 contiguous edges, all same src = tid>>1
    const int sl = tid >> 1;
    int dls[16];
#pragma unroll
    for (int j=0;j<16;j++) dls[j] = dP[e0+j] - abase;
    const float px = sPx[sl], py = sPy[sl], pz = sPz[sl];
    const float srs = sSr[sl];
    // ---- phase 1: Isum accumulation ----
#pragma unroll 2
    for (int j=0;j<16;j++){
        int dl = dls[j];
        float dx = px - sPx[dl], dy = py - sPy[dl], dz = pz - sPz[dl];
        float d = sqrtf(dx*dx+dy*dy+dz*dz + 1e-12f);
        float rho_i = sRho[dl];
        float U = d + srs;
        if (rho_i < U){
            float L = fmaxf(rho_i, fabsf(d - srs));
            float invU = 1.f/U, invL = 1.f/L;
            float I = 0.5f*invL - 0.5f*invU
                    + 0.125f*(d - srs*srs/d)*(invU*invU - invL*invL)
                    + 0.25f*__logf(L*invU)/d;
            atomicAdd(&sI[dl], I);
        }
    }
    __syncthreads();
    // ---- phase B: per-atom Born radius + self energy ----
    if (tid < 256){
        float rho = sRho[tid], rad = sRad[tid], q = sQ[tid];
        float psi = sI[tid]*rho;
        float uu = psi*(ALPHAC + psi*(-BETAC + GAMMAC*psi));
        float t = tanhf(uu);
        float B = 1.f/(1.f/rho - t/rad);
        sB[tid] = B;
        float du = ALPHAC + psi*(-2.f*BETAC + 3.f*GAMMAC*psi);
        scB[tid] = B*B*((1.f-t*t)/rad)*du*rho;
        float Cs = 0.5f*PREFC*q*q;
        sE[tid] = Cs/B;
        sgB[tid] = -Cs/(B*B);
    }
    __syncthreads();
    // ---- phase C: pair energies + dE/dB accumulation ----
    const float qs = sQ[sl], Bs = sB[sl];
    {
        float gsrc = 0.f;
#pragma unroll 2
        for (int j=0;j<16;j++){
            int dl = dls[j];
            float dx = px - sPx[dl], dy = py - sPy[dl], dz = pz - sPz[dl];
            float d2 = dx*dx+dy*dy+dz*dz + 1e-12f;
            float Bd = sB[dl];
            float C = 0.5f*PREFC*sQ[dl]*qs;
            float P = Bd*Bs;
            float ex = __expf(-d2/(4.f*P));
            float f2 = d2 + P*ex;
            float f = sqrtf(f2);
            atomicAdd(&sE[dl], C/f);
            float f3i = 1.f/(f2*f);
            float common = -C*ex*(1.f + d2/(4.f*P))*0.5f*f3i;
            atomicAdd(&sgB[dl], common*Bs);
            gsrc += common*Bd;
        }
        atomicAdd(&sgB[sl], gsrc);
    }
    __syncthreads();
    // ---- phase E: recompute per-edge grads, accumulate forces ----
    {
        float gx=0.f, gy=0.f, gz=0.f;
#pragma unroll 2
        for (int j=0;j<16;j++){
            int dl = dls[j];
            float dx = px - sPx[dl], dy = py - sPy[dl], dz = pz - sPz[dl];
            float d2 = dx*dx+dy*dy+dz*dz + 1e-12f;
            float d = sqrtf(d2);
            float Bd = sB[dl];
            float C = 0.5f*PREFC*sQ[dl]*qs;
            float P = Bd*Bs;
            float ex = __expf(-d2/(4.f*P));
            float f2 = d2 + P*ex;
            float f = sqrtf(f2);
            float f3i = 1.f/(f2*f);
            float gd = -C*d*(1.f - 0.25f*ex)*f3i;
            float rho_i = sRho[dl];
            float U = d + srs;
            if (rho_i < U){
                float aa = fabsf(d - srs);
                float L, Lp;
                if (rho_i >= aa){ L = rho_i; Lp = 0.f; }
                else { L = aa; Lp = (d >= srs) ? 1.f : -1.f; }
                float invU = 1.f/U, invL = 1.f/L;
                float invU2=invU*invU, invL2=invL*invL;
                float dIdd = -0.5f*Lp*invL2 + 0.5f*invU2
                    + 0.125f*(1.f + srs*srs/d2)*(invU2 - invL2)
                    + 0.125f*(d - srs*srs/d)*(2.f*Lp*invL2*invL - 2.f*invU2*invU)
                    + 0.25f*((Lp*invL - invU)/d - __logf(L*invU)/d2);
                gd += sgB[dl]*scB[dl]*dIdd;
            }
            float c = gd/d;
            gx += c*dx; gy += c*dy; gz += c*dz;
            atomicAdd(&sGx[dl], -c*dx);
            atomicAdd(&sGy[dl], -c*dy);
            atomicAdd(&sGz[dl], -c*dz);
        }
        atomicAdd(&sGx[sl], gx);
        atomicAdd(&sGy[sl], gy);
        atomicAdd(&sGz[sl], gz);
    }
    __syncthreads();
    // ---- write-out: grad (plain) + molecule GB energy (reduced) ----
    if (tid < 256){
        int i = abase + tid;
        grad[3*i+0] = sGx[tid];
        grad[3*i+1] = sGy[tid];
        grad[3*i+2] = sGz[tid];
        float v = waveRed(sE[tid]);
        if ((tid&63)==0) red[tid>>6] = v;
    }
    __syncthreads();
    if (tid==0) egbM[m] = red[0]+red[1]+red[2]+red[3];
}

// ============ GNN ============
__global__ __launch_bounds__(256) void k_dist(
    const float* __restrict__ pos, const int* __restrict__ gei,
    float* __restrict__ dgnn, int* __restrict__ cnt)
{
    int e = blockIdx.x*256 + threadIdx.x;
    if (e >= EGNN) return;
    int s = gei[e], dd = gei[EGNN+e];
    float dx = pos[3*s+0] - pos[3*dd+0];
    float dy = pos[3*s+1] - pos[3*dd+1];
    float dz = pos[3*s+2] - pos[3*dd+2];
    dgnn[e] = sqrtf(dx*dx+dy*dy+dz*dz + 1e-12f);
    atomicAdd(&cnt[dd], 1);
}

__global__ __launch_bounds__(256) void k_uv1(
    const float* __restrict__ feat, const float* __restrict__ A1,
    float* __restrict__ u1, float* __restrict__ v1)
{
    int gid = blockIdx.x*256 + threadIdx.x;
    int i = gid >> 7, k = gid & 127;
    float q = feat[7*i+0], r = feat[7*i+1];
    u1[gid] = q*A1[k]       + r*A1[HID+k];
    v1[gid] = q*A1[2*HID+k] + r*A1[3*HID+k];
}

__global__ __launch_bounds__(128) void k_uv(
    const float* __restrict__ x, const float* __restrict__ A,
    float* __restrict__ u, float* __restrict__ v)
{
    __shared__ float sx[4][HID];
    int k = threadIdx.x;
    int i0 = blockIdx.x*4;
    for (int t=0;t<4;t++) sx[t][k] = x[(i0+t)*HID+k];
    __syncthreads();
    float au0=0,au1=0,au2=0,au3=0, av0=0,av1=0,av2=0,av3=0;
    for (int j=0;j<HID;j++){
        float wa = A[j*HID+k];
        float wb = A[(HID+j)*HID+k];
        float x0=sx[0][j], x1=sx[1][j], x2=sx[2][j], x3=sx[3][j];
        au0+=x0*wa; au1+=x1*wa; au2+=x2*wa; au3+=x3*wa;
        av0+=x0*wb; av1+=x1*wb; av2+=x2*wb; av3+=x3*wb;
    }
    u[(i0+0)*HID+k]=au0; u[(i0+1)*HID+k]=au1; u[(i0+2)*HID+k]=au2; u[(i0+3)*HID+k]=au3;
    v[(i0+0)*HID+k]=av0; v[(i0+1)*HID+k]=av1; v[(i0+2)*HID+k]=av2; v[(i0+3)*HID+k]=av3;
}

// edge forward, per molecule-k-half; Hs accumulated in LDS, zero global atomics
__global__ __launch_bounds__(256) void k_edge_fwd_mol(
    const int* __restrict__ gei, const float* __restrict__ dgnn,
    const float* __restrict__ u, const float* __restrict__ v,
    const float* __restrict__ wdp, const float* __restrict__ bb,
    float* __restrict__ Hs)
{
    __shared__ float sHs[256*64];
    int m = blockIdx.x >> 1, kh = blockIdx.x & 1;
    int k = threadIdx.x & 63, w = threadIdx.x >> 6;
    int kk = kh*64 + k, abase = 256*m;
    for (int i=threadIdx.x; i<16384; i+=256) sHs[i]=0.f;
    __syncthreads();
    float wd = wdp[kk], bk = bb[kk];
    const int* dP = gei + EGNN + 4096*m;
    const float* dgp = dgnn + 4096*m;
    for (int sl=64*w; sl<64*w+64; ++sl){
        float uk = u[(abase+sl)*HID + kk];
        int e = sl*16;
#pragma unroll 4
        for (int j=0;j<16;j++){
            int dl = dP[e+j] - abase;
            float a = uk + v[(abase+dl)*HID+kk] + dgp[e+j]*wd + bk;
            atomicAdd(&sHs[dl*64+k], a*sigf(a));
        }
    }
    __syncthreads();
    for (int i=threadIdx.x; i<16384; i+=256){
        int at = i>>6, k2 = i&63;
        Hs[(abase+at)*HID + kh*64 + k2] = sHs[i];
    }
}

__global__ __launch_bounds__(128) void k_node_fwd(
    const float* __restrict__ Hs, const int* __restrict__ cnt,
    const float* __restrict__ C, const float* __restrict__ D,
    float* __restrict__ z, float* __restrict__ x)
{
    __shared__ float sh[4][HID];
    int k = threadIdx.x;
    int i0 = blockIdx.x*4;
    for (int t=0;t<4;t++) sh[t][k] = Hs[(i0+t)*HID+k];
    __syncthreads();
    float dk = D[k];
    float a0=cnt[i0+0]*dk, a1=cnt[i0+1]*dk, a2=cnt[i0+2]*dk, a3=cnt[i0+3]*dk;
    for (int j=0;j<HID;j++){
        float c = C[j*HID+k];
        a0+=sh[0][j]*c; a1+=sh[1][j]*c; a2+=sh[2][j]*c; a3+=sh[3][j]*c;
    }
    z[(i0+0)*HID+k]=a0; x[(i0+0)*HID+k]=a0*sigf(a0);
    z[(i0+1)*HID+k]=a1; x[(i0+1)*HID+k]=a1*sigf(a1);
    z[(i0+2)*HID+k]=a2; x[(i0+2)*HID+k]=a2*sigf(a2);
    z[(i0+3)*HID+k]=a3; x[(i0+3)*HID+k]=a3*sigf(a3);
}

// layer-3 fwd+bwd, per molecule-k-half
__global__ __launch_bounds__(256) void k_edge_l3_mol(
    const int* __restrict__ gei, const float* __restrict__ dgnn,
    const float* __restrict__ u, const float* __restrict__ v,
    const float* __restrict__ A3, const float* __restrict__ B3,
    const float* __restrict__ C3, const float* __restrict__ D3,
    float* __restrict__ x3, float* __restrict__ Gs, float* __restrict__ Gd,
    float* __restrict__ gdg)
{
    __shared__ float sGd[256*64];
    int m = blockIdx.x >> 1, kh = blockIdx.x & 1;
    int k = threadIdx.x & 63, w = threadIdx.x >> 6;
    int kk = kh*64 + k, abase = 256*m;
    for (int i=threadIdx.x; i<16384; i+=256) sGd[i]=0.f;
    __syncthreads();
    float wd = A3[256*HID+kk], bk = B3[kk], ck = C3[kk];
    float d3 = (kh==0) ? D3[0] : 0.f;
    const int* dP = gei + EGNN + 4096*m;
    const float* dgp = dgnn + 4096*m;
    float* gdgp = gdg + 4096*m;
    for (int sl=64*w; sl<64*w+64; ++sl){
        float uk = u[(abase+sl)*HID + kk];
        float gs = 0.f;
        int e = sl*16;
        for (int j=0;j<16;j++){
            int dl = dP[e+j] - abase;
            float a = uk + v[(abase+dl)*HID+kk] + dgp[e+j]*wd + bk;
            float sg = sigf(a);
            float h = a*sg;
            float ds = sg*(1.f + a*(1.f - sg));
            float ga = ck*ds;
            gs += ga;
            atomicAdd(&sGd[dl*64+k], ga);
            float pe = waveRed(h*ck);
            float pg = waveRed(ga*wd);
            if (k==0){
                atomicAdd(&x3[abase+dl], pe + d3);
                atomicAdd(&gdgp[e+j], pg);
            }
        }
        Gs[(abase+sl)*HID+kk] = gs;
    }
    __syncthreads();
    for (int i=threadIdx.x; i<16384; i+=256){
        int at = i>>6, k2 = i&63;
        Gd[(abase+at)*HID + kh*64 + k2] = sGd[i];
    }
}

__global__ __launch_bounds__(256) void k_edge_bwd_mol(
    const int* __restrict__ gei, const float* __restrict__ dgnn,
    const float* __restrict__ u, const float* __restrict__ v,
    const float* __restrict__ wdp, const float* __restrict__ bb,
    const float* __restrict__ gHin,
    float* __restrict__ Gs, float* __restrict__ Gd, float* __restrict__ gdg)
{
    __shared__ float sGd[256*64];
    int m = blockIdx.x >> 1, kh = blockIdx.x & 1;
    int k = threadIdx.x & 63, w = threadIdx.x >> 6;
    int kk = kh*64 + k, abase = 256*m;
    for (int i=threadIdx.x; i<16384; i+=256) sGd[i]=0.f;
    __syncthreads();
    float wd = wdp[kk], bk = bb[kk];
    const int* dP = gei + EGNN + 4096*m;
    const float* dgp = dgnn + 4096*m;
    float* gdgp = gdg + 4096*m;
    for (int sl=64*w; sl<64*w+64; ++sl){
        float uk = u[(abase+sl)*HID + kk];
        float gs = 0.f;
        int e = sl*16;
        for (int j=0;j<16;j++){
            int dl = dP[e+j] - abase;
            float a = uk + v[(abase+dl)*HID+kk] + dgp[e+j]*wd + bk;
            float sg = sigf(a);
            float ds = sg*(1.f + a*(1.f - sg));
            float ga = gHin[(abase+dl)*HID+kk]*ds;
            gs += ga;
            atomicAdd(&sGd[dl*64+k], ga);
            float pg = waveRed(ga*wd);
            if (k==0) atomicAdd(&gdgp[e+j], pg);
        }
        Gs[(abase+sl)*HID+kk] = gs;
    }
    __syncthreads();
    for (int i=threadIdx.x; i<16384; i+=256){
        int at = i>>6, k2 = i&63;
        Gd[(abase+at)*HID + kh*64 + k2] = sGd[i];
    }
}

__global__ __launch_bounds__(256) void k_edge_bwd1_mol(
    const int* __restrict__ gei, const float* __restrict__ dgnn,
    const float* __restrict__ u, const float* __restrict__ v,
    const float* __restrict__ wdp, const float* __restrict__ bb,
    const float* __restrict__ gHin, float* __restrict__ gdg)
{
    int m = blockIdx.x >> 1, kh = blockIdx.x & 1;
    int k = threadIdx.x & 63, w = threadIdx.x >> 6;
    int kk = kh*64 + k, abase = 256*m;
    float wd = wdp[kk], bk = bb[kk];
    const int* dP = gei + EGNN + 4096*m;
    const float* dgp = dgnn + 4096*m;
    float* gdgp = gdg + 4096*m;
    for (int sl=64*w; sl<64*w+64; ++sl){
        float uk = u[(abase+sl)*HID + kk];
        int e = sl*16;
        for (int j=0;j<16;j++){
            int dl = dP[e+j] - abase;
            float a = uk + v[(abase+dl)*HID+kk] + dgp[e+j]*wd + bk;
            float sg = sigf(a);
            float ds = sg*(1.f + a*(1.f - sg));
            float ga = gHin[(abase+dl)*HID+kk]*ds;
            float pg = waveRed(ga*wd);
            if (k==0) atomicAdd(&gdgp[e+j], pg);
        }
    }
}

// fused: gx = Gs@Aaᵀ + Gd@Abᵀ ; t = gx*silu'(z) ; gH = t@Cᵀ
__global__ __launch_bounds__(128) void k_gx_node_bwd(
    const float* __restrict__ Gs, const float* __restrict__ Gd,
    const float* __restrict__ A, const float* __restrict__ z,
    const float* __restrict__ C, float* __restrict__ gH)
{
    __shared__ float sGs[4][HID], sGdS[4][HID], sh2[4][HID];
    int j = threadIdx.x;
    int i0 = blockIdx.x*4;
    for (int t=0;t<4;t++){ sGs[t][j]=Gs[(i0+t)*HID+j]; sGdS[t][j]=Gd[(i0+t)*HID+j]; }
    __syncthreads();
    float a0=0,a1=0,a2=0,a3=0;
    const float* ra = A + j*HID;
    const float* rb = A + (HID+j)*HID;
    for (int k=0;k<HID;k++){
        float wa = ra[k], wb = rb[k];
        a0 += sGs[0][k]*wa + sGdS[0][k]*wb;
        a1 += sGs[1][k]*wa + sGdS[1][k]*wb;
        a2 += sGs[2][k]*wa + sGdS[2][k]*wb;
        a3 += sGs[3][k]*wa + sGdS[3][k]*wb;
    }
    {
        float zz,sg;
        zz=z[(i0+0)*HID+j]; sg=sigf(zz); sh2[0][j]=a0*sg*(1.0f+zz*(1.0f-sg));
        zz=z[(i0+1)*HID+j]; sg=sigf(zz); sh2[1][j]=a1*sg*(1.0f+zz*(1.0f-sg));
        zz=z[(i0+2)*HID+j]; sg=sigf(zz); sh2[2][j]=a2*sg*(1.0f+zz*(1.0f-sg));
        zz=z[(i0+3)*HID+j]; sg=sigf(zz); sh2[3][j]=a3*sg*(1.0f+zz*(1.0f-sg));
    }
    __syncthreads();
    float b0=0,b1=0,b2=0,b3=0;
    const float* rc = C + j*HID;
    for (int k=0;k<HID;k++){
        float wc = rc[k];
        b0+=sh2[0][k]*wc; b1+=sh2[1][k]*wc; b2+=sh2[2][k]*wc; b3+=sh2[3][k]*wc;
    }
    gH[(i0+0)*HID+j]=b0; gH[(i0+1)*HID+j]=b1; gH[(i0+2)*HID+j]=b2; gH[(i0+3)*HID+j]=b3;
}

// GNN forces, per molecule in LDS; plain rmw of grad (GB wrote base)
__global__ __launch_bounds__(256) void k_force_mol(
    const float* __restrict__ pos, const int* __restrict__ gei,
    const float* __restrict__ dgnn, const float* __restrict__ gdg,
    float* __restrict__ grad)
{
    __shared__ float sPx[256], sPy[256], sPz[256];
    __shared__ float sGx[256], sGy[256], sGz[256];
    int m = blockIdx.x, tid = threadIdx.x, abase = 256*m;
    int i = abase + tid;
    sPx[tid]=pos[3*i]; sPy[tid]=pos[3*i+1]; sPz[tid]=pos[3*i+2];
    sGx[tid]=0.f; sGy[tid]=0.f; sGz[tid]=0.f;
    __syncthreads();
    const int* dP = gei + EGNN + 4096*m;
    const float* dgp = dgnn + 4096*m;
    const float* ggp = gdg + 4096*m;
    float px=sPx[tid], py=sPy[tid], pz=sPz[tid];
    float ax=0.f, ay=0.f, az=0.f;
    int e0 = tid*16;
#pragma unroll 4
    for (int j=0;j<16;j++){
        int dl = dP[e0+j] - abase;
        float c = ggp[e0+j]/dgp[e0+j];
        float dx=px-sPx[dl], dy=py-sPy[dl], dz=pz-sPz[dl];
        ax += c*dx; ay += c*dy; az += c*dz;
        atomicAdd(&sGx[dl], -c*dx);
        atomicAdd(&sGy[dl], -c*dy);
        atomicAdd(&sGz[dl], -c*dz);
    }
    __syncthreads();
    grad[3*i+0] += ax + sGx[tid];
    grad[3*i+1] += ay + sGy[tid];
    grad[3*i+2] += az + sGz[tid];
}

__global__ __launch_bounds__(256) void k_final(
    const float* __restrict__ egbM, const float* __restrict__ x3,
    const float* __restrict__ grad, float* __restrict__ out)
{
    __shared__ float red[4];
    int m = blockIdx.x, tid = threadIdx.x;
    int i = m*ATOMSM + tid;
    float v = waveRed(x3[i]);
    int wave = tid>>6, lane = tid&63;
    if (lane==0) red[wave] = v;
    __syncthreads();
    if (tid==0) out[m] = egbM[m] + red[0]+red[1]+red[2]+red[3];
    float* f = out + MOLS;
    f[3*i+0] = -grad[3*i+0];
    f[3*i+1] = -grad[3*i+1];
    f[3*i+2] = -grad[3*i+2];
}

extern "C" void kernel_launch(void* const* d_in, const int* in_sizes, int n_in,
                              void* d_out, int out_size, void* d_ws, size_t ws_size,
                              hipStream_t stream)
{
    const float* pos  = (const float*)d_in[0];
    const float* feat = (const float*)d_in[1];
    const int* ei  = (const int*)d_in[3];
    const int* gei = (const int*)d_in[4];
    const float* A1f = (const float*)d_in[5];  const float* B1f = (const float*)d_in[6];
    const float* C1f = (const float*)d_in[7];  const float* D1f = (const float*)d_in[8];
    const float* A2f = (const float*)d_in[9];  const float* B2f = (const float*)d_in[10];
    const float* C2f = (const float*)d_in[11]; const float* D2f = (const float*)d_in[12];
    const float* A3f = (const float*)d_in[13]; const float* B3f = (const float*)d_in[14];
    const float* C3f = (const float*)d_in[15]; const float* D3f = (const float*)d_in[16];

    float* w = (float*)d_ws;
    size_t off = 0;
    auto nxt = [&](size_t n)->float*{ float* p = w + off; off += (n + 255) & ~(size_t)255; return p; };
    float* x3 = nxt(NATOMS); int* cnt = (int*)nxt(NATOMS);
    float* egbM = nxt(MOLS);
    float* dgnn = nxt(EGNN); float* gdgnn = nxt(EGNN);
    float* grad = nxt(3*NATOMS);
    float* u1 = nxt(NH); float* v1 = nxt(NH); float* z1 = nxt(NH); float* x1 = nxt(NH);
    float* Hs1 = nxt(NH);
    float* u2 = nxt(NH); float* v2 = nxt(NH); float* z2 = nxt(NH); float* x2 = nxt(NH);
    float* Hs2 = nxt(NH);
    float* v3 = nxt(NH);
    // aliases (lifetimes):
    float* Gd3 = x1;    // x1 free after k_uv(layer2)
    float* Gs3 = Hs1;   // Hs1 free after node_fwd1
    float* u3  = Hs2;   // Hs2 free after node_fwd2
    float* gH2 = Hs2;   // u3 free after k_edge_l3_mol
    float* Gd2 = v3;    // v3 free after k_edge_l3_mol
    float* Gs2 = x2;    // x2 free after k_uv(layer3)
    float* gH1 = Hs1;   // Gs3 free after gx_node_bwd(3->2)

    hipMemsetAsync(x3,    0, NATOMS*sizeof(float), stream);
    hipMemsetAsync(cnt,   0, NATOMS*sizeof(int), stream);
    hipMemsetAsync(gdgnn, 0, EGNN*sizeof(float), stream);

    // GB: one fused kernel, writes grad + per-molecule GB energy
    k_gb<<<MOLS,512,0,stream>>>(pos, feat, ei, grad, egbM);

    // GNN forward
    k_dist<<<EGNN/256,256,0,stream>>>(pos, gei, dgnn, cnt);
    k_uv1<<<NH/256,256,0,stream>>>(feat, A1f, u1, v1);
    k_edge_fwd_mol<<<2*MOLS,256,0,stream>>>(gei, dgnn, u1, v1, A1f+4*HID, B1f, Hs1);
    k_node_fwd<<<NATOMS/4,128,0,stream>>>(Hs1, cnt, C1f, D1f, z1, x1);
    k_uv<<<NATOMS/4,128,0,stream>>>(x1, A2f, u2, v2);
    k_edge_fwd_mol<<<2*MOLS,256,0,stream>>>(gei, dgnn, u2, v2, A2f+256*HID, B2f, Hs2);
    k_node_fwd<<<NATOMS/4,128,0,stream>>>(Hs2, cnt, C2f, D2f, z2, x2);
    k_uv<<<NATOMS/4,128,0,stream>>>(x2, A3f, u3, v3);

    // layer-3 fwd+bwd fused, then backward chain
    k_edge_l3_mol<<<2*MOLS,256,0,stream>>>(gei, dgnn, u3, v3, A3f, B3f, C3f, D3f,
                                           x3, Gs3, Gd3, gdgnn);
    k_gx_node_bwd<<<NATOMS/4,128,0,stream>>>(Gs3, Gd3, A3f, z2, C2f, gH2);
    k_edge_bwd_mol<<<2*MOLS,256,0,stream>>>(gei, dgnn, u2, v2, A2f+256*HID, B2f, gH2,
                                            Gs2, Gd2, gdgnn);
    k_gx_node_bwd<<<NATOMS/4,128,0,stream>>>(Gs2, Gd2, A2f, z1, C1f, gH1);
    k_edge_bwd1_mol<<<2*MOLS,256,0,stream>>>(gei, dgnn, u1, v1, A1f+4*HID, B1f, gH1, gdgnn);
    k_force_mol<<<MOLS,256,0,stream>>>(pos, gei, dgnn, gdgnn, grad);

    k_final<<<MOLS,256,0,stream>>>(egbM, x3, grad, (float*)d_out);
}

// Round 5
// 1120.108 us; speedup vs baseline: 3.4656x; 3.4656x over previous
//
#include <hip/hip_runtime.h>
#include <hip/hip_bf16.h>

#define NATOMS 16384
#define MOLS   64
#define ATOMSM 256
#define EGB    524288
#define EGNN   262144
#define HID    128
#define NH     (NATOMS*HID)

#define OFFSETC 0.009f
#define ALPHAC  1.0f
#define BETAC   0.8f
#define GAMMAC  4.85f
#define PREFC   (-138.935456f*(1.0f-1.0f/78.5f))

__device__ __forceinline__ float sigf(float x){ return 1.0f/(1.0f+__expf(-x)); }
__device__ __forceinline__ float waveRed(float v){
    v += __shfl_xor(v,32); v += __shfl_xor(v,16); v += __shfl_xor(v,8);
    v += __shfl_xor(v,4);  v += __shfl_xor(v,2);  v += __shfl_xor(v,1);
    return v;
}

// ---------------- GB part ----------------
// 1 thread per edge; Isum scatter is to random dst (low contention)
__global__ __launch_bounds__(256) void k_gbA(
    const float* __restrict__ pos, const float* __restrict__ feat,
    const int* __restrict__ ei, float* __restrict__ Isum)
{
    int e = blockIdx.x*256 + threadIdx.x;
    if (e >= EGB) return;
    int s = e >> 5;                       // src = repeat(arange, 32)
    int dd = ei[EGB+e];
    float dx = pos[3*s+0] - pos[3*dd+0];
    float dy = pos[3*s+1] - pos[3*dd+1];
    float dz = pos[3*s+2] - pos[3*dd+2];
    float d  = sqrtf(dx*dx+dy*dy+dz*dz + 1e-12f);
    float sr = feat[7*s+2] * (feat[7*s+1] - OFFSETC);
    float rho_i = feat[7*dd+1] - OFFSETC;
    float U = d + sr;
    if (rho_i < U){
        float L = fmaxf(rho_i, fabsf(d - sr));
        float invU = 1.0f/U, invL = 1.0f/L;
        float I = 0.5f*invL - 0.5f*invU
                + 0.125f*(d - sr*sr/d)*(invU*invU - invL*invL)
                + 0.25f*__logf(L*invU)/d;
        atomicAdd(&Isum[dd], I);
    }
}

__global__ __launch_bounds__(256) void k_gbB(
    const float* __restrict__ feat, const float* __restrict__ Isum,
    float* __restrict__ Bv, float* __restrict__ cB, float* __restrict__ gB,
    float* __restrict__ egb)
{
    int i = blockIdx.x*256 + threadIdx.x;
    if (i >= NATOMS) return;
    float q   = feat[7*i+0];
    float rad = feat[7*i+1];
    float rho = rad - OFFSETC;
    float psi = Isum[i]*rho;
    float u = psi*(ALPHAC + psi*(-BETAC + GAMMAC*psi));
    float t = tanhf(u);
    float B = 1.0f/(1.0f/rho - t/rad);
    Bv[i] = B;
    float du = ALPHAC + psi*(-2.0f*BETAC + 3.0f*GAMMAC*psi);
    cB[i] = B*B*((1.0f-t*t)/rad)*du*rho;
    float Cs = 0.5f*PREFC*q*q;
    egb[i] = Cs/B;
    gB[i]  = -Cs/(B*B);
}

// 4 edges/thread (8 threads/src): src-side gB accumulated in regs + shfl,
// one atomic per src. Dst-side atomics random -> low contention.
__global__ __launch_bounds__(256) void k_gbC(
    const float* __restrict__ pos, const float* __restrict__ feat,
    const int* __restrict__ ei, const float* __restrict__ Bv,
    float* __restrict__ egb, float* __restrict__ gdgb, float* __restrict__ gB)
{
    int T = blockIdx.x*256 + threadIdx.x;   // NATOMS*8 threads
    int s = T >> 3, p = T & 7;
    int e0 = s*32 + p*4;
    float px = pos[3*s+0], py = pos[3*s+1], pz = pos[3*s+2];
    float qs = feat[7*s+0];
    float Bs = Bv[s];
    float gsrc = 0.f;
    const int* dP = ei + EGB;
#pragma unroll
    for (int j=0;j<4;j++){
        int dd = dP[e0+j];
        float dx = px - pos[3*dd+0];
        float dy = py - pos[3*dd+1];
        float dz = pz - pos[3*dd+2];
        float d2 = dx*dx+dy*dy+dz*dz + 1e-12f;
        float d  = sqrtf(d2);
        float Bd = Bv[dd];
        float C = 0.5f*PREFC*feat[7*dd+0]*qs;
        float P = Bd*Bs;
        float ex = __expf(-d2/(4.f*P));
        float f2 = d2 + P*ex;
        float f  = sqrtf(f2);
        atomicAdd(&egb[dd], C/f);
        float f3i = 1.f/(f2*f);
        gdgb[e0+j] = -C*d*(1.f - 0.25f*ex)*f3i;
        float common = -C*ex*(1.f + d2/(4.f*P))*0.5f*f3i;
        atomicAdd(&gB[dd], common*Bs);
        gsrc += common*Bd;
    }
    gsrc += __shfl_xor(gsrc,1);
    gsrc += __shfl_xor(gsrc,2);
    gsrc += __shfl_xor(gsrc,4);
    if (p==0) atomicAdd(&gB[s], gsrc);
}

// fold gB into cB so gbE does one gather instead of two
__global__ __launch_bounds__(256) void k_gbD(
    const float* __restrict__ gB, float* __restrict__ cB)
{
    int i = blockIdx.x*256 + threadIdx.x;
    if (i < NATOMS) cB[i] *= gB[i];
}

// 4 edges/thread: src grad in regs + shfl, one atomic triple per src.
__global__ __launch_bounds__(256) void k_gbE(
    const float* __restrict__ pos, const float* __restrict__ feat,
    const int* __restrict__ ei, const float* __restrict__ cBg,
    const float* __restrict__ gdgb, float* __restrict__ grad)
{
    int T = blockIdx.x*256 + threadIdx.x;
    int s = T >> 3, p = T & 7;
    int e0 = s*32 + p*4;
    float px = pos[3*s+0], py = pos[3*s+1], pz = pos[3*s+2];
    float sr = feat[7*s+2] * (feat[7*s+1] - OFFSETC);
    float gx=0.f, gy=0.f, gz=0.f;
    const int* dP = ei + EGB;
#pragma unroll
    for (int j=0;j<4;j++){
        int dd = dP[e0+j];
        float dx = px - pos[3*dd+0];
        float dy = py - pos[3*dd+1];
        float dz = pz - pos[3*dd+2];
        float d2 = dx*dx+dy*dy+dz*dz + 1e-12f;
        float d  = sqrtf(d2);
        float rho_i = feat[7*dd+1] - OFFSETC;
        float U = d + sr;
        float gd = gdgb[e0+j];
        if (rho_i < U){
            float aa = fabsf(d - sr);
            float L, Lp;
            if (rho_i >= aa){ L = rho_i; Lp = 0.f; }
            else { L = aa; Lp = (d >= sr) ? 1.f : -1.f; }
            float invU = 1.f/U, invL = 1.f/L;
            float invU2=invU*invU, invL2=invL*invL;
            float dIdd = -0.5f*Lp*invL2 + 0.5f*invU2
                + 0.125f*(1.f + sr*sr/d2)*(invU2 - invL2)
                + 0.125f*(d - sr*sr/d)*(2.f*Lp*invL2*invL - 2.f*invU2*invU)
                + 0.25f*((Lp*invL - invU)/d - __logf(L*invU)/d2);
            gd += cBg[dd]*dIdd;
        }
        float c = gd/d;
        gx += c*dx; gy += c*dy; gz += c*dz;
        atomicAdd(&grad[3*dd+0], -c*dx);
        atomicAdd(&grad[3*dd+1], -c*dy);
        atomicAdd(&grad[3*dd+2], -c*dz);
    }
    gx += __shfl_xor(gx,1); gx += __shfl_xor(gx,2); gx += __shfl_xor(gx,4);
    gy += __shfl_xor(gy,1); gy += __shfl_xor(gy,2); gy += __shfl_xor(gy,4);
    gz += __shfl_xor(gz,1); gz += __shfl_xor(gz,2); gz += __shfl_xor(gz,4);
    if (p==0){
        atomicAdd(&grad[3*s+0], gx);
        atomicAdd(&grad[3*s+1], gy);
        atomicAdd(&grad[3*s+2], gz);
    }
}

// ---------------- GNN part (round-3 proven-fast versions) ----------------
__global__ __launch_bounds__(256) void k_dist(
    const float* __restrict__ pos, const int* __restrict__ gei,
    float* __restrict__ dgnn, int* __restrict__ cnt)
{
    int e = blockIdx.x*256 + threadIdx.x;
    if (e >= EGNN) return;
    int s = gei[e], dd = gei[EGNN+e];
    float dx = pos[3*s+0] - pos[3*dd+0];
    float dy = pos[3*s+1] - pos[3*dd+1];
    float dz = pos[3*s+2] - pos[3*dd+2];
    dgnn[e] = sqrtf(dx*dx+dy*dy+dz*dz + 1e-12f);
    atomicAdd(&cnt[dd], 1);
}

__global__ __launch_bounds__(256) void k_uv1(
    const float* __restrict__ feat, const float* __restrict__ A1,
    float* __restrict__ u1, float* __restrict__ v1)
{
    int gid = blockIdx.x*256 + threadIdx.x;
    int i = gid >> 7, k = gid & 127;
    float q = feat[7*i+0], r = feat[7*i+1];
    u1[gid] = q*A1[k]       + r*A1[HID+k];
    v1[gid] = q*A1[2*HID+k] + r*A1[3*HID+k];
}

__global__ __launch_bounds__(128) void k_uv(
    const float* __restrict__ x, const float* __restrict__ A,
    float* __restrict__ u, float* __restrict__ v)
{
    __shared__ float sx[4][HID];
    int k = threadIdx.x;
    int i0 = blockIdx.x*4;
    for (int t=0;t<4;t++) sx[t][k] = x[(i0+t)*HID+k];
    __syncthreads();
    float au0=0,au1=0,au2=0,au3=0, av0=0,av1=0,av2=0,av3=0;
    for (int j=0;j<HID;j++){
        float wa = A[j*HID+k];
        float wb = A[(HID+j)*HID+k];
        float x0=sx[0][j], x1=sx[1][j], x2=sx[2][j], x3=sx[3][j];
        au0+=x0*wa; au1+=x1*wa; au2+=x2*wa; au3+=x3*wa;
        av0+=x0*wb; av1+=x1*wb; av2+=x2*wb; av3+=x3*wb;
    }
    u[(i0+0)*HID+k]=au0; u[(i0+1)*HID+k]=au1; u[(i0+2)*HID+k]=au2; u[(i0+3)*HID+k]=au3;
    v[(i0+0)*HID+k]=av0; v[(i0+1)*HID+k]=av1; v[(i0+2)*HID+k]=av2; v[(i0+3)*HID+k]=av3;
}

__global__ __launch_bounds__(128) void k_edge_fwd(
    const int* __restrict__ gei, const float* __restrict__ dgnn,
    const float* __restrict__ u, const float* __restrict__ v,
    const float* __restrict__ wdp, const float* __restrict__ bb,
    float* __restrict__ Hs)
{
    int s = blockIdx.x, k = threadIdx.x;
    float uk = u[s*HID+k], wd = wdp[k], bk = bb[k];
    int e0 = s*16;
    int dsts[16]; float dv[16];
#pragma unroll
    for (int t=0;t<16;t++){ dsts[t]=gei[EGNN+e0+t]; dv[t]=dgnn[e0+t]; }
#pragma unroll 4
    for (int t=0;t<16;t++){
        float a = uk + v[dsts[t]*HID+k] + dv[t]*wd + bk;
        atomicAdd(&Hs[dsts[t]*HID+k], a*sigf(a));
    }
}

__global__ __launch_bounds__(128) void k_node_fwd(
    const float* __restrict__ Hs, const int* __restrict__ cnt,
    const float* __restrict__ C, const float* __restrict__ D,
    float* __restrict__ z, float* __restrict__ x)
{
    __shared__ float sh[4][HID];
    int k = threadIdx.x;
    int i0 = blockIdx.x*4;
    for (int t=0;t<4;t++) sh[t][k] = Hs[(i0+t)*HID+k];
    __syncthreads();
    float dk = D[k];
    float a0=cnt[i0+0]*dk, a1=cnt[i0+1]*dk, a2=cnt[i0+2]*dk, a3=cnt[i0+3]*dk;
    for (int j=0;j<HID;j++){
        float c = C[j*HID+k];
        a0+=sh[0][j]*c; a1+=sh[1][j]*c; a2+=sh[2][j]*c; a3+=sh[3][j]*c;
    }
    z[(i0+0)*HID+k]=a0; x[(i0+0)*HID+k]=a0*sigf(a0);
    z[(i0+1)*HID+k]=a1; x[(i0+1)*HID+k]=a1*sigf(a1);
    z[(i0+2)*HID+k]=a2; x[(i0+2)*HID+k]=a2*sigf(a2);
    z[(i0+3)*HID+k]=a3; x[(i0+3)*HID+k]=a3*sigf(a3);
}

__global__ __launch_bounds__(128) void k_edge_l3(
    const int* __restrict__ gei, const float* __restrict__ dgnn,
    const float* __restrict__ u, const float* __restrict__ v,
    const float* __restrict__ A3, const float* __restrict__ B3,
    const float* __restrict__ C3, const float* __restrict__ D3,
    float* __restrict__ x3, float* __restrict__ Gs, float* __restrict__ Gd,
    float* __restrict__ gdg)
{
    __shared__ float sE[2][16], sG[2][16];
    int s = blockIdx.x, k = threadIdx.x;
    int wave = k>>6, lane = k&63;
    float uk = u[s*HID+k], wd = A3[256*HID+k], bk = B3[k], ck = C3[k];
    int e0 = s*16;
    int dsts[16]; float dv[16];
#pragma unroll
    for (int t=0;t<16;t++){ dsts[t]=gei[EGNN+e0+t]; dv[t]=dgnn[e0+t]; }
    float gs = 0.0f;
#pragma unroll 4
    for (int t=0;t<16;t++){
        float a = uk + v[dsts[t]*HID+k] + dv[t]*wd + bk;
        float sg = sigf(a);
        float h = a*sg;
        float ds = sg*(1.0f + a*(1.0f - sg));
        float ga = ck*ds;
        gs += ga;
        atomicAdd(&Gd[dsts[t]*HID+k], ga);
        float pe = waveRed(h*ck);
        float pg = waveRed(ga*wd);
        if (lane==0){ sE[wave][t]=pe; sG[wave][t]=pg; }
    }
    Gs[s*HID+k] = gs;
    __syncthreads();
    if (k < 16){
        atomicAdd(&x3[dsts[k]], sE[0][k]+sE[1][k]+D3[0]);
        gdg[e0+k] = sG[0][k]+sG[1][k];
    }
}

__global__ __launch_bounds__(128) void k_edge_bwd(
    const int* __restrict__ gei, const float* __restrict__ dgnn,
    const float* __restrict__ u, const float* __restrict__ v,
    const float* __restrict__ wdp, const float* __restrict__ bb,
    const float* __restrict__ gHin,
    float* __restrict__ Gs, float* __restrict__ Gd, float* __restrict__ gdg)
{
    __shared__ float sG[2][16];
    int s = blockIdx.x, k = threadIdx.x;
    int wave=k>>6, lane=k&63;
    float uk = u[s*HID+k], wd = wdp[k], bk = bb[k];
    int e0 = s*16;
    int dsts[16]; float dv[16];
#pragma unroll
    for (int t=0;t<16;t++){ dsts[t]=gei[EGNN+e0+t]; dv[t]=dgnn[e0+t]; }
    float gs = 0.0f;
#pragma unroll 4
    for (int t=0;t<16;t++){
        float a = uk + v[dsts[t]*HID+k] + dv[t]*wd + bk;
        float sg = sigf(a);
        float ds = sg*(1.0f + a*(1.0f - sg));
        float ga = gHin[dsts[t]*HID+k]*ds;
        gs += ga;
        atomicAdd(&Gd[dsts[t]*HID+k], ga);
        float pg = waveRed(ga*wd);
        if (lane==0) sG[wave][t]=pg;
    }
    Gs[s*HID+k] = gs;
    __syncthreads();
    if (k < 16) gdg[e0+k] += sG[0][k]+sG[1][k];
}

__global__ __launch_bounds__(128) void k_edge_bwd1(
    const int* __restrict__ gei, const float* __restrict__ dgnn,
    const float* __restrict__ u, const float* __restrict__ v,
    const float* __restrict__ wdp, const float* __restrict__ bb,
    const float* __restrict__ gHin, float* __restrict__ gdg)
{
    __shared__ float sG[2][16];
    int s = blockIdx.x, k = threadIdx.x;
    int wave=k>>6, lane=k&63;
    float uk = u[s*HID+k], wd = wdp[k], bk = bb[k];
    int e0 = s*16;
    int dsts[16]; float dv[16];
#pragma unroll
    for (int t=0;t<16;t++){ dsts[t]=gei[EGNN+e0+t]; dv[t]=dgnn[e0+t]; }
#pragma unroll 4
    for (int t=0;t<16;t++){
        float a = uk + v[dsts[t]*HID+k] + dv[t]*wd + bk;
        float sg = sigf(a);
        float ds = sg*(1.0f + a*(1.0f - sg));
        float ga = gHin[dsts[t]*HID+k]*ds;
        float pg = waveRed(ga*wd);
        if (lane==0) sG[wave][t]=pg;
    }
    __syncthreads();
    if (k < 16) gdg[e0+k] += sG[0][k]+sG[1][k];
}

__global__ __launch_bounds__(128) void k_gx_node_bwd(
    const float* __restrict__ Gs, const float* __restrict__ Gd,
    const float* __restrict__ A, const float* __restrict__ z,
    const float* __restrict__ C, float* __restrict__ gH)
{
    __shared__ float sGs[4][HID], sGdS[4][HID], sh2[4][HID];
    int j = threadIdx.x;
    int i0 = blockIdx.x*4;
    for (int t=0;t<4;t++){ sGs[t][j]=Gs[(i0+t)*HID+j]; sGdS[t][j]=Gd[(i0+t)*HID+j]; }
    __syncthreads();
    float a0=0,a1=0,a2=0,a3=0;
    const float* ra = A + j*HID;
    const float* rb = A + (HID+j)*HID;
    for (int k=0;k<HID;k++){
        float wa = ra[k], wb = rb[k];
        a0 += sGs[0][k]*wa + sGdS[0][k]*wb;
        a1 += sGs[1][k]*wa + sGdS[1][k]*wb;
        a2 += sGs[2][k]*wa + sGdS[2][k]*wb;
        a3 += sGs[3][k]*wa + sGdS[3][k]*wb;
    }
    {
        float zz,sg;
        zz=z[(i0+0)*HID+j]; sg=sigf(zz); sh2[0][j]=a0*sg*(1.0f+zz*(1.0f-sg));
        zz=z[(i0+1)*HID+j]; sg=sigf(zz); sh2[1][j]=a1*sg*(1.0f+zz*(1.0f-sg));
        zz=z[(i0+2)*HID+j]; sg=sigf(zz); sh2[2][j]=a2*sg*(1.0f+zz*(1.0f-sg));
        zz=z[(i0+3)*HID+j]; sg=sigf(zz); sh2[3][j]=a3*sg*(1.0f+zz*(1.0f-sg));
    }
    __syncthreads();
    float b0=0,b1=0,b2=0,b3=0;
    const float* rc = C + j*HID;
    for (int k=0;k<HID;k++){
        float wc = rc[k];
        b0+=sh2[0][k]*wc; b1+=sh2[1][k]*wc; b2+=sh2[2][k]*wc; b3+=sh2[3][k]*wc;
    }
    gH[(i0+0)*HID+j]=b0; gH[(i0+1)*HID+j]=b1; gH[(i0+2)*HID+j]=b2; gH[(i0+3)*HID+j]=b3;
}

// GNN forces: 4 edges/thread (4 threads/src), shfl-reduce src side
__global__ __launch_bounds__(256) void k_force_gnn(
    const float* __restrict__ pos, const int* __restrict__ gei,
    const float* __restrict__ dgnn, const float* __restrict__ gdg,
    float* __restrict__ grad)
{
    int T = blockIdx.x*256 + threadIdx.x;    // NATOMS*4 threads
    int s = T >> 2, p = T & 3;
    int e0 = s*16 + p*4;
    float px = pos[3*s+0], py = pos[3*s+1], pz = pos[3*s+2];
    float gx=0.f, gy=0.f, gz=0.f;
    const int* dP = gei + EGNN;
#pragma unroll
    for (int j=0;j<4;j++){
        int dd = dP[e0+j];
        float c = gdg[e0+j]/dgnn[e0+j];
        float dx=px-pos[3*dd+0], dy=py-pos[3*dd+1], dz=pz-pos[3*dd+2];
        gx += c*dx; gy += c*dy; gz += c*dz;
        atomicAdd(&grad[3*dd+0], -c*dx);
        atomicAdd(&grad[3*dd+1], -c*dy);
        atomicAdd(&grad[3*dd+2], -c*dz);
    }
    gx += __shfl_xor(gx,1); gx += __shfl_xor(gx,2);
    gy += __shfl_xor(gy,1); gy += __shfl_xor(gy,2);
    gz += __shfl_xor(gz,1); gz += __shfl_xor(gz,2);
    if (p==0){
        atomicAdd(&grad[3*s+0], gx);
        atomicAdd(&grad[3*s+1], gy);
        atomicAdd(&grad[3*s+2], gz);
    }
}

__global__ __launch_bounds__(256) void k_final(
    const float* __restrict__ egb, const float* __restrict__ x3,
    const float* __restrict__ grad, float* __restrict__ out)
{
    __shared__ float red[4];
    int m = blockIdx.x, tid = threadIdx.x;
    int i = m*ATOMSM + tid;
    float en = egb[i] + x3[i];
    float v = waveRed(en);
    int wave = tid>>6, lane = tid&63;
    if (lane==0) red[wave] = v;
    __syncthreads();
    if (tid==0) out[m] = red[0]+red[1]+red[2]+red[3];
    float* f = out + MOLS;
    f[3*i+0] = -grad[3*i+0];
    f[3*i+1] = -grad[3*i+1];
    f[3*i+2] = -grad[3*i+2];
}

extern "C" void kernel_launch(void* const* d_in, const int* in_sizes, int n_in,
                              void* d_out, int out_size, void* d_ws, size_t ws_size,
                              hipStream_t stream)
{
    const float* pos  = (const float*)d_in[0];
    const float* feat = (const float*)d_in[1];
    const int* ei  = (const int*)d_in[3];
    const int* gei = (const int*)d_in[4];
    const float* A1f = (const float*)d_in[5];  const float* B1f = (const float*)d_in[6];
    const float* C1f = (const float*)d_in[7];  const float* D1f = (const float*)d_in[8];
    const float* A2f = (const float*)d_in[9];  const float* B2f = (const float*)d_in[10];
    const float* C2f = (const float*)d_in[11]; const float* D2f = (const float*)d_in[12];
    const float* A3f = (const float*)d_in[13]; const float* B3f = (const float*)d_in[14];
    const float* C3f = (const float*)d_in[15]; const float* D3f = (const float*)d_in[16];

    float* w = (float*)d_ws;
    size_t off = 0;
    auto nxt = [&](size_t n)->float*{ float* p = w + off; off += (n + 255) & ~(size_t)255; return p; };
    float* Isum = nxt(NATOMS); float* Bv = nxt(NATOMS); float* cB = nxt(NATOMS);
    float* gB = nxt(NATOMS); float* egb = nxt(NATOMS); float* x3 = nxt(NATOMS);
    int*   cnt = (int*)nxt(NATOMS);
    float* dgnn = nxt(EGNN); float* gdgnn = nxt(EGNN); float* gdgb = nxt(EGB);
    float* grad = nxt(3*NATOMS);
    float* u1 = nxt(NH); float* v1 = nxt(NH); float* z1 = nxt(NH); float* x1 = nxt(NH);
    float* Hs1 = nxt(NH);
    float* u2 = nxt(NH); float* v2 = nxt(NH); float* z2 = nxt(NH); float* x2 = nxt(NH);
    float* Hs2 = nxt(NH);
    float* v3 = nxt(NH);
    // aliases (lifetimes verified in round 3):
    float* Gd3 = x1;    // x1 free after k_uv(layer2)
    float* Gs3 = Hs1;   // Hs1 free after node_fwd1
    float* u3  = Hs2;   // Hs2 free after node_fwd2
    float* gH2 = Hs2;   // u3 free after k_edge_l3
    float* Gd2 = v3;    // v3 free after k_edge_l3
    float* Gs2 = x2;    // x2 free after k_uv(layer3)
    float* gH1 = Hs1;   // Gs3 free after gx_node_bwd(3->2)

    hipMemsetAsync(Isum, 0, NATOMS*sizeof(float), stream);
    hipMemsetAsync(x3,   0, NATOMS*sizeof(float), stream);
    hipMemsetAsync(cnt,  0, NATOMS*sizeof(int), stream);
    hipMemsetAsync(grad, 0, 3*NATOMS*sizeof(float), stream);
    hipMemsetAsync(Hs1,  0, (size_t)NH*sizeof(float), stream);
    hipMemsetAsync(Hs2,  0, (size_t)NH*sizeof(float), stream);

    // GB chain (contention-fixed)
    k_gbA<<<EGB/256,256,0,stream>>>(pos, feat, ei, Isum);
    k_gbB<<<NATOMS/256,256,0,stream>>>(feat, Isum, Bv, cB, gB, egb);
    k_gbC<<<NATOMS*8/256,256,0,stream>>>(pos, feat, ei, Bv, egb, gdgb, gB);
    k_gbD<<<NATOMS/256,256,0,stream>>>(gB, cB);
    k_gbE<<<NATOMS*8/256,256,0,stream>>>(pos, feat, ei, cB, gdgb, grad);

    // GNN forward
    k_dist<<<EGNN/256,256,0,stream>>>(pos, gei, dgnn, cnt);
    k_uv1<<<NH/256,256,0,stream>>>(feat, A1f, u1, v1);
    k_edge_fwd<<<NATOMS,128,0,stream>>>(gei, dgnn, u1, v1, A1f+4*HID, B1f, Hs1);
    k_node_fwd<<<NATOMS/4,128,0,stream>>>(Hs1, cnt, C1f, D1f, z1, x1);
    k_uv<<<NATOMS/4,128,0,stream>>>(x1, A2f, u2, v2);
    hipMemsetAsync(Gd3, 0, (size_t)NH*sizeof(float), stream);    // x1 dead now
    k_edge_fwd<<<NATOMS,128,0,stream>>>(gei, dgnn, u2, v2, A2f+256*HID, B2f, Hs2);
    k_node_fwd<<<NATOMS/4,128,0,stream>>>(Hs2, cnt, C2f, D2f, z2, x2);
    k_uv<<<NATOMS/4,128,0,stream>>>(x2, A3f, u3, v3);            // u3 aliases Hs2 (dead)

    // layer-3 fwd+bwd fused
    k_edge_l3<<<NATOMS,128,0,stream>>>(gei, dgnn, u3, v3, A3f, B3f, C3f, D3f,
                                       x3, Gs3, Gd3, gdgnn);
    hipMemsetAsync(Gd2, 0, (size_t)NH*sizeof(float), stream);    // v3 dead now

    // backward chain
    k_gx_node_bwd<<<NATOMS/4,128,0,stream>>>(Gs3, Gd3, A3f, z2, C2f, gH2);
    k_edge_bwd<<<NATOMS,128,0,stream>>>(gei, dgnn, u2, v2, A2f+256*HID, B2f, gH2,
                                        Gs2, Gd2, gdgnn);
    k_gx_node_bwd<<<NATOMS/4,128,0,stream>>>(Gs2, Gd2, A2f, z1, C1f, gH1);
    k_edge_bwd1<<<NATOMS,128,0,stream>>>(gei, dgnn, u1, v1, A1f+4*HID, B1f, gH1, gdgnn);
    k_force_gnn<<<NATOMS*4/256,256,0,stream>>>(pos, gei, dgnn, gdgnn, grad);

    k_final<<<MOLS,256,0,stream>>>(egb, x3, grad, (float*)d_out);
}

// Round 6
// 953.022 us; speedup vs baseline: 4.0732x; 1.1753x over previous
//
#include <hip/hip_runtime.h>
#include <hip/hip_bf16.h>

#define NATOMS 16384
#define MOLS   64
#define ATOMSM 256
#define EGB    524288
#define EGNN   262144
#define HID    128
#define NH     (NATOMS*HID)
#define NPB    8

#define OFFSETC 0.009f
#define ALPHAC  1.0f
#define BETAC   0.8f
#define GAMMAC  4.85f
#define PREFC   (-138.935456f*(1.0f-1.0f/78.5f))

__device__ __forceinline__ float sigf(float x){ return 1.0f/(1.0f+__expf(-x)); }
__device__ __forceinline__ float waveRed(float v){
    v += __shfl_xor(v,32); v += __shfl_xor(v,16); v += __shfl_xor(v,8);
    v += __shfl_xor(v,4);  v += __shfl_xor(v,2);  v += __shfl_xor(v,1);
    return v;
}

// ---------------- GB part (round-5 proven) ----------------
__global__ __launch_bounds__(256) void k_gbA(
    const float* __restrict__ pos, const float* __restrict__ feat,
    const int* __restrict__ ei, float* __restrict__ Isum)
{
    int e = blockIdx.x*256 + threadIdx.x;
    if (e >= EGB) return;
    int s = e >> 5;
    int dd = ei[EGB+e];
    float dx = pos[3*s+0] - pos[3*dd+0];
    float dy = pos[3*s+1] - pos[3*dd+1];
    float dz = pos[3*s+2] - pos[3*dd+2];
    float d  = sqrtf(dx*dx+dy*dy+dz*dz + 1e-12f);
    float sr = feat[7*s+2] * (feat[7*s+1] - OFFSETC);
    float rho_i = feat[7*dd+1] - OFFSETC;
    float U = d + sr;
    if (rho_i < U){
        float L = fmaxf(rho_i, fabsf(d - sr));
        float invU = 1.0f/U, invL = 1.0f/L;
        float I = 0.5f*invL - 0.5f*invU
                + 0.125f*(d - sr*sr/d)*(invU*invU - invL*invL)
                + 0.25f*__logf(L*invU)/d;
        atomicAdd(&Isum[dd], I);
    }
}

__global__ __launch_bounds__(256) void k_gbB(
    const float* __restrict__ feat, const float* __restrict__ Isum,
    float* __restrict__ Bv, float* __restrict__ cB, float* __restrict__ gB,
    float* __restrict__ egb)
{
    int i = blockIdx.x*256 + threadIdx.x;
    if (i >= NATOMS) return;
    float q   = feat[7*i+0];
    float rad = feat[7*i+1];
    float rho = rad - OFFSETC;
    float psi = Isum[i]*rho;
    float u = psi*(ALPHAC + psi*(-BETAC + GAMMAC*psi));
    float t = tanhf(u);
    float B = 1.0f/(1.0f/rho - t/rad);
    Bv[i] = B;
    float du = ALPHAC + psi*(-2.0f*BETAC + 3.0f*GAMMAC*psi);
    cB[i] = B*B*((1.0f-t*t)/rad)*du*rho;
    float Cs = 0.5f*PREFC*q*q;
    egb[i] = Cs/B;
    gB[i]  = -Cs/(B*B);
}

__global__ __launch_bounds__(256) void k_gbC(
    const float* __restrict__ pos, const float* __restrict__ feat,
    const int* __restrict__ ei, const float* __restrict__ Bv,
    float* __restrict__ egb, float* __restrict__ gdgb, float* __restrict__ gB)
{
    int T = blockIdx.x*256 + threadIdx.x;
    int s = T >> 3, p = T & 7;
    int e0 = s*32 + p*4;
    float px = pos[3*s+0], py = pos[3*s+1], pz = pos[3*s+2];
    float qs = feat[7*s+0];
    float Bs = Bv[s];
    float gsrc = 0.f;
    const int* dP = ei + EGB;
#pragma unroll
    for (int j=0;j<4;j++){
        int dd = dP[e0+j];
        float dx = px - pos[3*dd+0];
        float dy = py - pos[3*dd+1];
        float dz = pz - pos[3*dd+2];
        float d2 = dx*dx+dy*dy+dz*dz + 1e-12f;
        float d  = sqrtf(d2);
        float Bd = Bv[dd];
        float C = 0.5f*PREFC*feat[7*dd+0]*qs;
        float P = Bd*Bs;
        float ex = __expf(-d2/(4.f*P));
        float f2 = d2 + P*ex;
        float f  = sqrtf(f2);
        atomicAdd(&egb[dd], C/f);
        float f3i = 1.f/(f2*f);
        gdgb[e0+j] = -C*d*(1.f - 0.25f*ex)*f3i;
        float common = -C*ex*(1.f + d2/(4.f*P))*0.5f*f3i;
        atomicAdd(&gB[dd], common*Bs);
        gsrc += common*Bd;
    }
    gsrc += __shfl_xor(gsrc,1);
    gsrc += __shfl_xor(gsrc,2);
    gsrc += __shfl_xor(gsrc,4);
    if (p==0) atomicAdd(&gB[s], gsrc);
}

__global__ __launch_bounds__(256) void k_gbD(
    const float* __restrict__ gB, float* __restrict__ cB)
{
    int i = blockIdx.x*256 + threadIdx.x;
    if (i < NATOMS) cB[i] *= gB[i];
}

__global__ __launch_bounds__(256) void k_gbE(
    const float* __restrict__ pos, const float* __restrict__ feat,
    const int* __restrict__ ei, const float* __restrict__ cBg,
    const float* __restrict__ gdgb, float* __restrict__ grad)
{
    int T = blockIdx.x*256 + threadIdx.x;
    int s = T >> 3, p = T & 7;
    int e0 = s*32 + p*4;
    float px = pos[3*s+0], py = pos[3*s+1], pz = pos[3*s+2];
    float sr = feat[7*s+2] * (feat[7*s+1] - OFFSETC);
    float gx=0.f, gy=0.f, gz=0.f;
    const int* dP = ei + EGB;
#pragma unroll
    for (int j=0;j<4;j++){
        int dd = dP[e0+j];
        float dx = px - pos[3*dd+0];
        float dy = py - pos[3*dd+1];
        float dz = pz - pos[3*dd+2];
        float d2 = dx*dx+dy*dy+dz*dz + 1e-12f;
        float d  = sqrtf(d2);
        float rho_i = feat[7*dd+1] - OFFSETC;
        float U = d + sr;
        float gd = gdgb[e0+j];
        if (rho_i < U){
            float aa = fabsf(d - sr);
            float L, Lp;
            if (rho_i >= aa){ L = rho_i; Lp = 0.f; }
            else { L = aa; Lp = (d >= sr) ? 1.f : -1.f; }
            float invU = 1.f/U, invL = 1.f/L;
            float invU2=invU*invU, invL2=invL*invL;
            float dIdd = -0.5f*Lp*invL2 + 0.5f*invU2
                + 0.125f*(1.f + sr*sr/d2)*(invU2 - invL2)
                + 0.125f*(d - sr*sr/d)*(2.f*Lp*invL2*invL - 2.f*invU2*invU)
                + 0.25f*((Lp*invL - invU)/d - __logf(L*invU)/d2);
            gd += cBg[dd]*dIdd;
        }
        float c = gd/d;
        gx += c*dx; gy += c*dy; gz += c*dz;
        atomicAdd(&grad[3*dd+0], -c*dx);
        atomicAdd(&grad[3*dd+1], -c*dy);
        atomicAdd(&grad[3*dd+2], -c*dz);
    }
    gx += __shfl_xor(gx,1); gx += __shfl_xor(gx,2); gx += __shfl_xor(gx,4);
    gy += __shfl_xor(gy,1); gy += __shfl_xor(gy,2); gy += __shfl_xor(gy,4);
    gz += __shfl_xor(gz,1); gz += __shfl_xor(gz,2); gz += __shfl_xor(gz,4);
    if (p==0){
        atomicAdd(&grad[3*s+0], gx);
        atomicAdd(&grad[3*s+1], gy);
        atomicAdd(&grad[3*s+2], gz);
    }
}

// ---------------- GNN part ----------------
__global__ __launch_bounds__(256) void k_dist(
    const float* __restrict__ pos, const int* __restrict__ gei,
    float* __restrict__ dgnn, int* __restrict__ cnt)
{
    int e = blockIdx.x*256 + threadIdx.x;
    if (e >= EGNN) return;
    int s = gei[e], dd = gei[EGNN+e];
    float dx = pos[3*s+0] - pos[3*dd+0];
    float dy = pos[3*s+1] - pos[3*dd+1];
    float dz = pos[3*s+2] - pos[3*dd+2];
    dgnn[e] = sqrtf(dx*dx+dy*dy+dz*dz + 1e-12f);
    atomicAdd(&cnt[dd], 1);
}

__global__ __launch_bounds__(256) void k_uv1(
    const float* __restrict__ feat, const float* __restrict__ A1,
    float* __restrict__ u1, float* __restrict__ v1)
{
    int gid = blockIdx.x*256 + threadIdx.x;
    int i = gid >> 7, k = gid & 127;
    float q = feat[7*i+0], r = feat[7*i+1];
    u1[gid] = q*A1[k]       + r*A1[HID+k];
    v1[gid] = q*A1[2*HID+k] + r*A1[3*HID+k];
}

__global__ __launch_bounds__(128) void k_edge_fwd(
    const int* __restrict__ gei, const float* __restrict__ dgnn,
    const float* __restrict__ u, const float* __restrict__ v,
    const float* __restrict__ wdp, const float* __restrict__ bb,
    float* __restrict__ Hs)
{
    int s = blockIdx.x, k = threadIdx.x;
    float uk = u[s*HID+k], wd = wdp[k], bk = bb[k];
    int e0 = s*16;
    int dsts[16]; float dv[16];
#pragma unroll
    for (int t=0;t<16;t++){ dsts[t]=gei[EGNN+e0+t]; dv[t]=dgnn[e0+t]; }
#pragma unroll 4
    for (int t=0;t<16;t++){
        float a = uk + v[dsts[t]*HID+k] + dv[t]*wd + bk;
        atomicAdd(&Hs[dsts[t]*HID+k], a*sigf(a));
    }
}

// fused node forward + next-layer projections:
// z = Hs@C + cnt*D ; x = silu(z) ; u = x@An[0:128] ; v = x@An[128:256]
__global__ __launch_bounds__(128) void k_node_fwd_uv(
    const float* __restrict__ Hs, const int* __restrict__ cnt,
    const float* __restrict__ C, const float* __restrict__ D,
    const float* __restrict__ An,
    float* __restrict__ z, float* __restrict__ u, float* __restrict__ v)
{
    __shared__ float sh[NPB][HID];
    __shared__ float sx[NPB][HID];
    int k = threadIdx.x;
    int i0 = blockIdx.x*NPB;
#pragma unroll
    for (int t=0;t<NPB;t++) sh[t][k] = Hs[(i0+t)*HID+k];
    __syncthreads();
    float dk = D[k];
    float a[NPB];
#pragma unroll
    for (int t=0;t<NPB;t++) a[t] = (float)cnt[i0+t]*dk;
#pragma unroll 4
    for (int j=0;j<HID;j++){
        float c = C[j*HID+k];
#pragma unroll
        for (int t=0;t<NPB;t++) a[t] += sh[t][j]*c;
    }
#pragma unroll
    for (int t=0;t<NPB;t++){
        z[(i0+t)*HID+k] = a[t];
        float sg = sigf(a[t]);
        sx[t][k] = a[t]*sg;
    }
    __syncthreads();
    float au[NPB], av[NPB];
#pragma unroll
    for (int t=0;t<NPB;t++){ au[t]=0.f; av[t]=0.f; }
#pragma unroll 4
    for (int j=0;j<HID;j++){
        float wa = An[j*HID+k], wb = An[(HID+j)*HID+k];
#pragma unroll
        for (int t=0;t<NPB;t++){ au[t] += sx[t][j]*wa; av[t] += sx[t][j]*wb; }
    }
#pragma unroll
    for (int t=0;t<NPB;t++){ u[(i0+t)*HID+k]=au[t]; v[(i0+t)*HID+k]=av[t]; }
}

// layer-3 fwd+bwd, LDS-transpose reduction instead of per-edge waveRed
__global__ __launch_bounds__(128) void k_edge_l3(
    const int* __restrict__ gei, const float* __restrict__ dgnn,
    const float* __restrict__ u, const float* __restrict__ v,
    const float* __restrict__ A3, const float* __restrict__ B3,
    const float* __restrict__ C3, const float* __restrict__ D3,
    float* __restrict__ x3, float* __restrict__ Gs, float* __restrict__ Gd,
    float* __restrict__ gdg)
{
    __shared__ float sP[16][130];
    __shared__ float sQ[16][130];
    int s = blockIdx.x, k = threadIdx.x;
    float uk = u[s*HID+k], wd = A3[256*HID+k], bk = B3[k], ck = C3[k];
    int e0 = s*16;
    int dsts[16]; float dv[16];
#pragma unroll
    for (int t=0;t<16;t++){ dsts[t]=gei[EGNN+e0+t]; dv[t]=dgnn[e0+t]; }
    float gs = 0.0f;
#pragma unroll 4
    for (int t=0;t<16;t++){
        float a = uk + v[dsts[t]*HID+k] + dv[t]*wd + bk;
        float sg = sigf(a);
        float h = a*sg;
        float ds = sg*(1.0f + a*(1.0f - sg));
        float ga = ck*ds;
        gs += ga;
        atomicAdd(&Gd[dsts[t]*HID+k], ga);
        sP[t][k] = h*ck;
        sQ[t][k] = ga*wd;
    }
    Gs[s*HID+k] = gs;
    __syncthreads();
    int t = k >> 3, r = k & 7;
    float pe = 0.f, pg = 0.f;
#pragma unroll
    for (int i=0;i<16;i++){ pe += sP[t][i + 16*r]; pg += sQ[t][i + 16*r]; }
    pe += __shfl_xor(pe,1); pe += __shfl_xor(pe,2); pe += __shfl_xor(pe,4);
    pg += __shfl_xor(pg,1); pg += __shfl_xor(pg,2); pg += __shfl_xor(pg,4);
    if (r==0){
        int dd = gei[EGNN+e0+t];
        atomicAdd(&x3[dd], pe + D3[0]);
        gdg[e0+t] = pg;
    }
}

__global__ __launch_bounds__(128) void k_edge_bwd(
    const int* __restrict__ gei, const float* __restrict__ dgnn,
    const float* __restrict__ u, const float* __restrict__ v,
    const float* __restrict__ wdp, const float* __restrict__ bb,
    const float* __restrict__ gHin,
    float* __restrict__ Gs, float* __restrict__ Gd, float* __restrict__ gdg)
{
    __shared__ float sQ[16][130];
    int s = blockIdx.x, k = threadIdx.x;
    float uk = u[s*HID+k], wd = wdp[k], bk = bb[k];
    int e0 = s*16;
    int dsts[16]; float dv[16];
#pragma unroll
    for (int t=0;t<16;t++){ dsts[t]=gei[EGNN+e0+t]; dv[t]=dgnn[e0+t]; }
    float gs = 0.0f;
#pragma unroll 4
    for (int t=0;t<16;t++){
        float a = uk + v[dsts[t]*HID+k] + dv[t]*wd + bk;
        float sg = sigf(a);
        float ds = sg*(1.0f + a*(1.0f - sg));
        float ga = gHin[dsts[t]*HID+k]*ds;
        gs += ga;
        atomicAdd(&Gd[dsts[t]*HID+k], ga);
        sQ[t][k] = ga*wd;
    }
    Gs[s*HID+k] = gs;
    __syncthreads();
    int t = k >> 3, r = k & 7;
    float pg = 0.f;
#pragma unroll
    for (int i=0;i<16;i++) pg += sQ[t][i + 16*r];
    pg += __shfl_xor(pg,1); pg += __shfl_xor(pg,2); pg += __shfl_xor(pg,4);
    if (r==0) gdg[e0+t] += pg;
}

__global__ __launch_bounds__(128) void k_edge_bwd1(
    const int* __restrict__ gei, const float* __restrict__ dgnn,
    const float* __restrict__ u, const float* __restrict__ v,
    const float* __restrict__ wdp, const float* __restrict__ bb,
    const float* __restrict__ gHin, float* __restrict__ gdg)
{
    __shared__ float sQ[16][130];
    int s = blockIdx.x, k = threadIdx.x;
    float uk = u[s*HID+k], wd = wdp[k], bk = bb[k];
    int e0 = s*16;
    int dsts[16]; float dv[16];
#pragma unroll
    for (int t=0;t<16;t++){ dsts[t]=gei[EGNN+e0+t]; dv[t]=dgnn[e0+t]; }
#pragma unroll 4
    for (int t=0;t<16;t++){
        float a = uk + v[dsts[t]*HID+k] + dv[t]*wd + bk;
        float sg = sigf(a);
        float ds = sg*(1.0f + a*(1.0f - sg));
        float ga = gHin[dsts[t]*HID+k]*ds;
        sQ[t][k] = ga*wd;
    }
    __syncthreads();
    int t = k >> 3, r = k & 7;
    float pg = 0.f;
#pragma unroll
    for (int i=0;i<16;i++) pg += sQ[t][i + 16*r];
    pg += __shfl_xor(pg,1); pg += __shfl_xor(pg,2); pg += __shfl_xor(pg,4);
    if (r==0) gdg[e0+t] += pg;
}

// gx = Gs@Aaᵀ + Gd@Abᵀ ; t = gx*silu'(z) ; gH = t@Cᵀ ; NPB nodes/block
__global__ __launch_bounds__(128) void k_gx_node_bwd(
    const float* __restrict__ Gs, const float* __restrict__ Gd,
    const float* __restrict__ A, const float* __restrict__ z,
    const float* __restrict__ C, float* __restrict__ gH)
{
    __shared__ float sGs[NPB][HID], sGd[NPB][HID], sh2[NPB][HID];
    int j = threadIdx.x;
    int i0 = blockIdx.x*NPB;
#pragma unroll
    for (int t=0;t<NPB;t++){ sGs[t][j]=Gs[(i0+t)*HID+j]; sGd[t][j]=Gd[(i0+t)*HID+j]; }
    __syncthreads();
    float a[NPB];
#pragma unroll
    for (int t=0;t<NPB;t++) a[t]=0.f;
    const float* ra = A + j*HID;
    const float* rb = A + (HID+j)*HID;
#pragma unroll 4
    for (int k=0;k<HID;k++){
        float wa = ra[k], wb = rb[k];
#pragma unroll
        for (int t=0;t<NPB;t++) a[t] += sGs[t][k]*wa + sGd[t][k]*wb;
    }
#pragma unroll
    for (int t=0;t<NPB;t++){
        float zz = z[(i0+t)*HID+j];
        float sg = sigf(zz);
        sh2[t][j] = a[t]*sg*(1.0f+zz*(1.0f-sg));
    }
    __syncthreads();
    float b[NPB];
#pragma unroll
    for (int t=0;t<NPB;t++) b[t]=0.f;
    const float* rc = C + j*HID;
#pragma unroll 4
    for (int k=0;k<HID;k++){
        float wc = rc[k];
#pragma unroll
        for (int t=0;t<NPB;t++) b[t] += sh2[t][k]*wc;
    }
#pragma unroll
    for (int t=0;t<NPB;t++) gH[(i0+t)*HID+j]=b[t];
}

__global__ __launch_bounds__(256) void k_force_gnn(
    const float* __restrict__ pos, const int* __restrict__ gei,
    const float* __restrict__ dgnn, const float* __restrict__ gdg,
    float* __restrict__ grad)
{
    int T = blockIdx.x*256 + threadIdx.x;
    int s = T >> 2, p = T & 3;
    int e0 = s*16 + p*4;
    float px = pos[3*s+0], py = pos[3*s+1], pz = pos[3*s+2];
    float gx=0.f, gy=0.f, gz=0.f;
    const int* dP = gei + EGNN;
#pragma unroll
    for (int j=0;j<4;j++){
        int dd = dP[e0+j];
        float c = gdg[e0+j]/dgnn[e0+j];
        float dx=px-pos[3*dd+0], dy=py-pos[3*dd+1], dz=pz-pos[3*dd+2];
        gx += c*dx; gy += c*dy; gz += c*dz;
        atomicAdd(&grad[3*dd+0], -c*dx);
        atomicAdd(&grad[3*dd+1], -c*dy);
        atomicAdd(&grad[3*dd+2], -c*dz);
    }
    gx += __shfl_xor(gx,1); gx += __shfl_xor(gx,2);
    gy += __shfl_xor(gy,1); gy += __shfl_xor(gy,2);
    gz += __shfl_xor(gz,1); gz += __shfl_xor(gz,2);
    if (p==0){
        atomicAdd(&grad[3*s+0], gx);
        atomicAdd(&grad[3*s+1], gy);
        atomicAdd(&grad[3*s+2], gz);
    }
}

__global__ __launch_bounds__(256) void k_final(
    const float* __restrict__ egb, const float* __restrict__ x3,
    const float* __restrict__ grad, float* __restrict__ out)
{
    __shared__ float red[4];
    int m = blockIdx.x, tid = threadIdx.x;
    int i = m*ATOMSM + tid;
    float en = egb[i] + x3[i];
    float v = waveRed(en);
    int wave = tid>>6, lane = tid&63;
    if (lane==0) red[wave] = v;
    __syncthreads();
    if (tid==0) out[m] = red[0]+red[1]+red[2]+red[3];
    float* f = out + MOLS;
    f[3*i+0] = -grad[3*i+0];
    f[3*i+1] = -grad[3*i+1];
    f[3*i+2] = -grad[3*i+2];
}

extern "C" void kernel_launch(void* const* d_in, const int* in_sizes, int n_in,
                              void* d_out, int out_size, void* d_ws, size_t ws_size,
                              hipStream_t stream)
{
    const float* pos  = (const float*)d_in[0];
    const float* feat = (const float*)d_in[1];
    const int* ei  = (const int*)d_in[3];
    const int* gei = (const int*)d_in[4];
    const float* A1f = (const float*)d_in[5];  const float* B1f = (const float*)d_in[6];
    const float* C1f = (const float*)d_in[7];  const float* D1f = (const float*)d_in[8];
    const float* A2f = (const float*)d_in[9];  const float* B2f = (const float*)d_in[10];
    const float* C2f = (const float*)d_in[11]; const float* D2f = (const float*)d_in[12];
    const float* A3f = (const float*)d_in[13]; const float* B3f = (const float*)d_in[14];
    const float* C3f = (const float*)d_in[15]; const float* D3f = (const float*)d_in[16];

    float* w = (float*)d_ws;
    size_t off = 0;
    auto nxt = [&](size_t n)->float*{ float* p = w + off; off += (n + 255) & ~(size_t)255; return p; };
    float* Isum = nxt(NATOMS); float* Bv = nxt(NATOMS); float* cB = nxt(NATOMS);
    float* gB = nxt(NATOMS); float* egb = nxt(NATOMS); float* x3 = nxt(NATOMS);
    int*   cnt = (int*)nxt(NATOMS);
    float* dgnn = nxt(EGNN); float* gdgnn = nxt(EGNN); float* gdgb = nxt(EGB);
    float* grad = nxt(3*NATOMS);
    float* u1 = nxt(NH); float* v1 = nxt(NH); float* z1 = nxt(NH); float* Hs1 = nxt(NH);
    float* u2 = nxt(NH); float* v2 = nxt(NH); float* z2 = nxt(NH); float* Hs2 = nxt(NH);
    float* v3 = nxt(NH); float* Gs3 = nxt(NH); float* Gd3 = nxt(NH);
    // aliases (lifetimes):
    float* u3  = Hs1;   // Hs1 dead after node_fwd_uv(layer1->2)... wait: Hs1 read in step 5; u3 written step 7
    float* gH2 = Hs2;   // Hs2 dead after node_fwd_uv(layer2->3); gH2 written by gx_node_bwd(3->2)
    float* Gs2 = Gs3;   // Gs3/Gd3 dead after gx_node_bwd(3->2)
    float* Gd2 = Gd3;
    float* gH1 = u3;    // u3 (=Hs1) dead after k_edge_l3; gH1 written by gx_node_bwd(2->1)

    hipMemsetAsync(Isum, 0, NATOMS*sizeof(float), stream);
    hipMemsetAsync(x3,   0, NATOMS*sizeof(float), stream);
    hipMemsetAsync(cnt,  0, NATOMS*sizeof(int), stream);
    hipMemsetAsync(grad, 0, 3*NATOMS*sizeof(float), stream);
    hipMemsetAsync(Hs1,  0, (size_t)NH*sizeof(float), stream);
    hipMemsetAsync(Hs2,  0, (size_t)NH*sizeof(float), stream);
    hipMemsetAsync(Gd3,  0, (size_t)NH*sizeof(float), stream);

    // GB chain
    k_gbA<<<EGB/256,256,0,stream>>>(pos, feat, ei, Isum);
    k_gbB<<<NATOMS/256,256,0,stream>>>(feat, Isum, Bv, cB, gB, egb);
    k_gbC<<<NATOMS*8/256,256,0,stream>>>(pos, feat, ei, Bv, egb, gdgb, gB);
    k_gbD<<<NATOMS/256,256,0,stream>>>(gB, cB);
    k_gbE<<<NATOMS*8/256,256,0,stream>>>(pos, feat, ei, cB, gdgb, grad);

    // GNN forward
    k_dist<<<EGNN/256,256,0,stream>>>(pos, gei, dgnn, cnt);
    k_uv1<<<NH/256,256,0,stream>>>(feat, A1f, u1, v1);
    k_edge_fwd<<<NATOMS,128,0,stream>>>(gei, dgnn, u1, v1, A1f+4*HID, B1f, Hs1);
    k_node_fwd_uv<<<NATOMS/NPB,128,0,stream>>>(Hs1, cnt, C1f, D1f, A2f, z1, u2, v2);
    k_edge_fwd<<<NATOMS,128,0,stream>>>(gei, dgnn, u2, v2, A2f+256*HID, B2f, Hs2);
    k_node_fwd_uv<<<NATOMS/NPB,128,0,stream>>>(Hs2, cnt, C2f, D2f, A3f, z2, u3, v3);

    // layer-3 fwd+bwd fused
    k_edge_l3<<<NATOMS,128,0,stream>>>(gei, dgnn, u3, v3, A3f, B3f, C3f, D3f,
                                       x3, Gs3, Gd3, gdgnn);

    // backward chain
    k_gx_node_bwd<<<NATOMS/NPB,128,0,stream>>>(Gs3, Gd3, A3f, z2, C2f, gH2);
    hipMemsetAsync(Gd2, 0, (size_t)NH*sizeof(float), stream);   // Gd3 dead now
    k_edge_bwd<<<NATOMS,128,0,stream>>>(gei, dgnn, u2, v2, A2f+256*HID, B2f, gH2,
                                        Gs2, Gd2, gdgnn);
    k_gx_node_bwd<<<NATOMS/NPB,128,0,stream>>>(Gs2, Gd2, A2f, z1, C1f, gH1);
    k_edge_bwd1<<<NATOMS,128,0,stream>>>(gei, dgnn, u1, v1, A1f+4*HID, B1f, gH1, gdgnn);
    k_force_gnn<<<NATOMS*4/256,256,0,stream>>>(pos, gei, dgnn, gdgnn, grad);

    k_final<<<MOLS,256,0,stream>>>(egb, x3, grad, (float*)d_out);
}

// Round 7
// 608.486 us; speedup vs baseline: 6.3794x; 1.5662x over previous
//
#include <hip/hip_runtime.h>
#include <hip/hip_bf16.h>

#define NATOMS 16384
#define MOLS   64
#define ATOMSM 256
#define EGB    524288
#define EGNN   262144
#define HID    128
#define NH     (NATOMS*HID)
#define NPB    8

#define OFFSETC 0.009f
#define ALPHAC  1.0f
#define BETAC   0.8f
#define GAMMAC  4.85f
#define PREFC   (-138.935456f*(1.0f-1.0f/78.5f))

typedef __hip_bfloat16 bf;
__device__ __forceinline__ float b2f(bf x){ return __bfloat162float(x); }
__device__ __forceinline__ bf f2b(float x){ return __float2bfloat16(x); }
__device__ __forceinline__ float sigf(float x){ return 1.0f/(1.0f+__expf(-x)); }
__device__ __forceinline__ float waveRed(float v){
    v += __shfl_xor(v,32); v += __shfl_xor(v,16); v += __shfl_xor(v,8);
    v += __shfl_xor(v,4);  v += __shfl_xor(v,2);  v += __shfl_xor(v,1);
    return v;
}

// ---------------- GB part (round-5 proven) ----------------
__global__ __launch_bounds__(256) void k_gbA(
    const float* __restrict__ pos, const float* __restrict__ feat,
    const int* __restrict__ ei, float* __restrict__ Isum)
{
    int e = blockIdx.x*256 + threadIdx.x;
    if (e >= EGB) return;
    int s = e >> 5;
    int dd = ei[EGB+e];
    float dx = pos[3*s+0] - pos[3*dd+0];
    float dy = pos[3*s+1] - pos[3*dd+1];
    float dz = pos[3*s+2] - pos[3*dd+2];
    float d  = sqrtf(dx*dx+dy*dy+dz*dz + 1e-12f);
    float sr = feat[7*s+2] * (feat[7*s+1] - OFFSETC);
    float rho_i = feat[7*dd+1] - OFFSETC;
    float U = d + sr;
    if (rho_i < U){
        float L = fmaxf(rho_i, fabsf(d - sr));
        float invU = 1.0f/U, invL = 1.0f/L;
        float I = 0.5f*invL - 0.5f*invU
                + 0.125f*(d - sr*sr/d)*(invU*invU - invL*invL)
                + 0.25f*__logf(L*invU)/d;
        atomicAdd(&Isum[dd], I);
    }
}

__global__ __launch_bounds__(256) void k_gbB(
    const float* __restrict__ feat, const float* __restrict__ Isum,
    float* __restrict__ Bv, float* __restrict__ cB, float* __restrict__ gB,
    float* __restrict__ egb)
{
    int i = blockIdx.x*256 + threadIdx.x;
    if (i >= NATOMS) return;
    float q   = feat[7*i+0];
    float rad = feat[7*i+1];
    float rho = rad - OFFSETC;
    float psi = Isum[i]*rho;
    float u = psi*(ALPHAC + psi*(-BETAC + GAMMAC*psi));
    float t = tanhf(u);
    float B = 1.0f/(1.0f/rho - t/rad);
    Bv[i] = B;
    float du = ALPHAC + psi*(-2.0f*BETAC + 3.0f*GAMMAC*psi);
    cB[i] = B*B*((1.0f-t*t)/rad)*du*rho;
    float Cs = 0.5f*PREFC*q*q;
    egb[i] = Cs/B;
    gB[i]  = -Cs/(B*B);
}

__global__ __launch_bounds__(256) void k_gbC(
    const float* __restrict__ pos, const float* __restrict__ feat,
    const int* __restrict__ ei, const float* __restrict__ Bv,
    float* __restrict__ egb, float* __restrict__ gdgb, float* __restrict__ gB)
{
    int T = blockIdx.x*256 + threadIdx.x;
    int s = T >> 3, p = T & 7;
    int e0 = s*32 + p*4;
    float px = pos[3*s+0], py = pos[3*s+1], pz = pos[3*s+2];
    float qs = feat[7*s+0];
    float Bs = Bv[s];
    float gsrc = 0.f;
    const int* dP = ei + EGB;
#pragma unroll
    for (int j=0;j<4;j++){
        int dd = dP[e0+j];
        float dx = px - pos[3*dd+0];
        float dy = py - pos[3*dd+1];
        float dz = pz - pos[3*dd+2];
        float d2 = dx*dx+dy*dy+dz*dz + 1e-12f;
        float d  = sqrtf(d2);
        float Bd = Bv[dd];
        float C = 0.5f*PREFC*feat[7*dd+0]*qs;
        float P = Bd*Bs;
        float ex = __expf(-d2/(4.f*P));
        float f2 = d2 + P*ex;
        float f  = sqrtf(f2);
        atomicAdd(&egb[dd], C/f);
        float f3i = 1.f/(f2*f);
        gdgb[e0+j] = -C*d*(1.f - 0.25f*ex)*f3i;
        float common = -C*ex*(1.f + d2/(4.f*P))*0.5f*f3i;
        atomicAdd(&gB[dd], common*Bs);
        gsrc += common*Bd;
    }
    gsrc += __shfl_xor(gsrc,1);
    gsrc += __shfl_xor(gsrc,2);
    gsrc += __shfl_xor(gsrc,4);
    if (p==0) atomicAdd(&gB[s], gsrc);
}

__global__ __launch_bounds__(256) void k_gbD(
    const float* __restrict__ gB, float* __restrict__ cB)
{
    int i = blockIdx.x*256 + threadIdx.x;
    if (i < NATOMS) cB[i] *= gB[i];
}

__global__ __launch_bounds__(256) void k_gbE(
    const float* __restrict__ pos, const float* __restrict__ feat,
    const int* __restrict__ ei, const float* __restrict__ cBg,
    const float* __restrict__ gdgb, float* __restrict__ grad)
{
    int T = blockIdx.x*256 + threadIdx.x;
    int s = T >> 3, p = T & 7;
    int e0 = s*32 + p*4;
    float px = pos[3*s+0], py = pos[3*s+1], pz = pos[3*s+2];
    float sr = feat[7*s+2] * (feat[7*s+1] - OFFSETC);
    float gx=0.f, gy=0.f, gz=0.f;
    const int* dP = ei + EGB;
#pragma unroll
    for (int j=0;j<4;j++){
        int dd = dP[e0+j];
        float dx = px - pos[3*dd+0];
        float dy = py - pos[3*dd+1];
        float dz = pz - pos[3*dd+2];
        float d2 = dx*dx+dy*dy+dz*dz + 1e-12f;
        float d  = sqrtf(d2);
        float rho_i = feat[7*dd+1] - OFFSETC;
        float U = d + sr;
        float gd = gdgb[e0+j];
        if (rho_i < U){
            float aa = fabsf(d - sr);
            float L, Lp;
            if (rho_i >= aa){ L = rho_i; Lp = 0.f; }
            else { L = aa; Lp = (d >= sr) ? 1.f : -1.f; }
            float invU = 1.f/U, invL = 1.f/L;
            float invU2=invU*invU, invL2=invL*invL;
            float dIdd = -0.5f*Lp*invL2 + 0.5f*invU2
                + 0.125f*(1.f + sr*sr/d2)*(invU2 - invL2)
                + 0.125f*(d - sr*sr/d)*(2.f*Lp*invL2*invL - 2.f*invU2*invU)
                + 0.25f*((Lp*invL - invU)/d - __logf(L*invU)/d2);
            gd += cBg[dd]*dIdd;
        }
        float c = gd/d;
        gx += c*dx; gy += c*dy; gz += c*dz;
        atomicAdd(&grad[3*dd+0], -c*dx);
        atomicAdd(&grad[3*dd+1], -c*dy);
        atomicAdd(&grad[3*dd+2], -c*dz);
    }
    gx += __shfl_xor(gx,1); gx += __shfl_xor(gx,2); gx += __shfl_xor(gx,4);
    gy += __shfl_xor(gy,1); gy += __shfl_xor(gy,2); gy += __shfl_xor(gy,4);
    gz += __shfl_xor(gz,1); gz += __shfl_xor(gz,2); gz += __shfl_xor(gz,4);
    if (p==0){
        atomicAdd(&grad[3*s+0], gx);
        atomicAdd(&grad[3*s+1], gy);
        atomicAdd(&grad[3*s+2], gz);
    }
}

// ---------------- GNN: dist + CSR build ----------------
__global__ __launch_bounds__(256) void k_dist(
    const float* __restrict__ pos, const int* __restrict__ gei,
    float* __restrict__ dgnn, int* __restrict__ cnt)
{
    int e = blockIdx.x*256 + threadIdx.x;
    if (e >= EGNN) return;
    int s = gei[e], dd = gei[EGNN+e];
    float dx = pos[3*s+0] - pos[3*dd+0];
    float dy = pos[3*s+1] - pos[3*dd+1];
    float dz = pos[3*s+2] - pos[3*dd+2];
    dgnn[e] = sqrtf(dx*dx+dy*dy+dz*dz + 1e-12f);
    atomicAdd(&cnt[dd], 1);
}

__global__ __launch_bounds__(256) void k_scan(
    const int* __restrict__ cnt, int* __restrict__ rptr, int* __restrict__ cursor)
{
    __shared__ int sc[256];
    int m = blockIdx.x, t = threadIdx.x;
    int c = cnt[m*256+t];
    sc[t] = c; __syncthreads();
    for (int off=1; off<256; off<<=1){
        int x = (t>=off) ? sc[t-off] : 0;
        __syncthreads();
        sc[t] += x;
        __syncthreads();
    }
    int ex = m*4096 + sc[t] - c;
    rptr[m*256+t] = ex;
    cursor[m*256+t] = ex;
}

__global__ __launch_bounds__(256) void k_fill(
    const int* __restrict__ gei, int* __restrict__ cursor, int* __restrict__ csr)
{
    int e = blockIdx.x*256 + threadIdx.x;
    if (e >= EGNN) return;
    int dst = gei[EGNN+e];
    int pos = atomicAdd(&cursor[dst], 1);
    csr[pos] = e;
}

// ---------------- GNN compute ----------------
__global__ __launch_bounds__(256) void k_uv1(
    const float* __restrict__ feat, const float* __restrict__ A1,
    bf* __restrict__ u1, bf* __restrict__ v1)
{
    int gid = blockIdx.x*256 + threadIdx.x;
    int i = gid >> 7, k = gid & 127;
    float q = feat[7*i+0], r = feat[7*i+1];
    u1[gid] = f2b(q*A1[k]       + r*A1[HID+k]);
    v1[gid] = f2b(q*A1[2*HID+k] + r*A1[3*HID+k]);
}

// dst-centric edge forward: Hs[dst] = sum_e silu(u[src]+v[dst]+d*wd+b), no atomics
__global__ __launch_bounds__(128) void k_edge_fwd_dst(
    const int* __restrict__ csr, const int* __restrict__ rptr, const int* __restrict__ cnt,
    const float* __restrict__ dgnn, const bf* __restrict__ u, const bf* __restrict__ v,
    const float* __restrict__ wdp, const float* __restrict__ bb,
    float* __restrict__ Hs)
{
    __shared__ int ss[128]; __shared__ float sd[128];
    int dst = blockIdx.x, k = threadIdx.x;
    int n = cnt[dst], r0 = rptr[dst];
    if (k < n){ int e = csr[r0+k]; ss[k] = e>>4; sd[k] = dgnn[e]; }
    __syncthreads();
    float vk = b2f(v[dst*HID+k]), wd = wdp[k], bk = bb[k];
    float hsum = 0.f;
    for (int j=0;j<n;j++){
        float a = b2f(u[ss[j]*HID+k]) + vk + sd[j]*wd + bk;
        hsum += a*sigf(a);
    }
    Hs[dst*HID+k] = hsum;
}

// node fwd + next-layer projections, bf16 u/v outputs
__global__ __launch_bounds__(128) void k_node_fwd_uv(
    const float* __restrict__ Hs, const int* __restrict__ cnt,
    const float* __restrict__ C, const float* __restrict__ D,
    const float* __restrict__ An,
    float* __restrict__ z, bf* __restrict__ u, bf* __restrict__ v)
{
    __shared__ float sh[NPB][HID];
    __shared__ float sx[NPB][HID];
    int k = threadIdx.x;
    int i0 = blockIdx.x*NPB;
#pragma unroll
    for (int t=0;t<NPB;t++) sh[t][k] = Hs[(i0+t)*HID+k];
    __syncthreads();
    float dk = D[k];
    float a[NPB];
#pragma unroll
    for (int t=0;t<NPB;t++) a[t] = (float)cnt[i0+t]*dk;
#pragma unroll 4
    for (int j=0;j<HID;j++){
        float c = C[j*HID+k];
#pragma unroll
        for (int t=0;t<NPB;t++) a[t] += sh[t][j]*c;
    }
#pragma unroll
    for (int t=0;t<NPB;t++){
        z[(i0+t)*HID+k] = a[t];
        float sg = sigf(a[t]);
        sx[t][k] = a[t]*sg;
    }
    __syncthreads();
    float au[NPB], av[NPB];
#pragma unroll
    for (int t=0;t<NPB;t++){ au[t]=0.f; av[t]=0.f; }
#pragma unroll 4
    for (int j=0;j<HID;j++){
        float wa = An[j*HID+k], wb = An[(HID+j)*HID+k];
#pragma unroll
        for (int t=0;t<NPB;t++){ au[t] += sx[t][j]*wa; av[t] += sx[t][j]*wb; }
    }
#pragma unroll
    for (int t=0;t<NPB;t++){ u[(i0+t)*HID+k]=f2b(au[t]); v[(i0+t)*HID+k]=f2b(av[t]); }
}

// l3 src pass: Gs (plain) + gdg (plain) — no atomics
__global__ __launch_bounds__(128) void k_l3_src(
    const int* __restrict__ gei, const float* __restrict__ dgnn,
    const bf* __restrict__ u, const bf* __restrict__ v,
    const float* __restrict__ A3, const float* __restrict__ B3,
    const float* __restrict__ C3,
    float* __restrict__ Gs, float* __restrict__ gdg)
{
    __shared__ float sQ[16][130];
    int s = blockIdx.x, k = threadIdx.x;
    float uk = b2f(u[s*HID+k]), wd = A3[256*HID+k], bk = B3[k], ck = C3[k];
    int e0 = s*16;
    int dsts[16]; float dv[16];
#pragma unroll
    for (int t=0;t<16;t++){ dsts[t]=gei[EGNN+e0+t]; dv[t]=dgnn[e0+t]; }
    float gs = 0.f;
#pragma unroll 4
    for (int t=0;t<16;t++){
        float a = uk + b2f(v[dsts[t]*HID+k]) + dv[t]*wd + bk;
        float sg = sigf(a);
        float ds = sg*(1.f + a*(1.f - sg));
        float ga = ck*ds;
        gs += ga;
        sQ[t][k] = ga*wd;
    }
    Gs[s*HID+k] = gs;
    __syncthreads();
    int t = k >> 3, r = k & 7;
    float pg = 0.f;
#pragma unroll
    for (int i=0;i<16;i++) pg += sQ[t][i + 16*r];
    pg += __shfl_xor(pg,1); pg += __shfl_xor(pg,2); pg += __shfl_xor(pg,4);
    if (r==0) gdg[e0+t] = pg;
}

// l3 dst pass: Gd (plain) + x3 (plain) — no atomics
__global__ __launch_bounds__(128) void k_l3_dst(
    const int* __restrict__ csr, const int* __restrict__ rptr, const int* __restrict__ cnt,
    const float* __restrict__ dgnn, const bf* __restrict__ u, const bf* __restrict__ v,
    const float* __restrict__ A3, const float* __restrict__ B3,
    const float* __restrict__ C3, const float* __restrict__ D3,
    float* __restrict__ Gd, float* __restrict__ x3)
{
    __shared__ int ss[128]; __shared__ float sd[128]; __shared__ float rr[2];
    int dst = blockIdx.x, k = threadIdx.x;
    int n = cnt[dst], r0 = rptr[dst];
    if (k < n){ int e = csr[r0+k]; ss[k] = e>>4; sd[k] = dgnn[e]; }
    __syncthreads();
    float vk = b2f(v[dst*HID+k]), wd = A3[256*HID+k], bk = B3[k], ck = C3[k];
    float hsum = 0.f, dssum = 0.f;
    for (int j=0;j<n;j++){
        float a = b2f(u[ss[j]*HID+k]) + vk + sd[j]*wd + bk;
        float sg = sigf(a);
        hsum += a*sg;
        dssum += sg*(1.f + a*(1.f - sg));
    }
    Gd[dst*HID+k] = ck*dssum;
    float pv = waveRed(ck*hsum);
    if ((k&63)==0) rr[k>>6] = pv;
    __syncthreads();
    if (k==0) x3[dst] = rr[0] + rr[1] + (float)n*D3[0];
}

// layer-2 bwd src pass
__global__ __launch_bounds__(128) void k_bwd_src(
    const int* __restrict__ gei, const float* __restrict__ dgnn,
    const bf* __restrict__ u, const bf* __restrict__ v,
    const float* __restrict__ wdp, const float* __restrict__ bb,
    const bf* __restrict__ gH,
    float* __restrict__ Gs, float* __restrict__ gdg)
{
    __shared__ float sQ[16][130];
    int s = blockIdx.x, k = threadIdx.x;
    float uk = b2f(u[s*HID+k]), wd = wdp[k], bk = bb[k];
    int e0 = s*16;
    int dsts[16]; float dv[16];
#pragma unroll
    for (int t=0;t<16;t++){ dsts[t]=gei[EGNN+e0+t]; dv[t]=dgnn[e0+t]; }
    float gs = 0.f;
#pragma unroll 4
    for (int t=0;t<16;t++){
        float a = uk + b2f(v[dsts[t]*HID+k]) + dv[t]*wd + bk;
        float sg = sigf(a);
        float ds = sg*(1.f + a*(1.f - sg));
        float ga = b2f(gH[dsts[t]*HID+k])*ds;
        gs += ga;
        sQ[t][k] = ga*wd;
    }
    Gs[s*HID+k] = gs;
    __syncthreads();
    int t = k >> 3, r = k & 7;
    float pg = 0.f;
#pragma unroll
    for (int i=0;i<16;i++) pg += sQ[t][i + 16*r];
    pg += __shfl_xor(pg,1); pg += __shfl_xor(pg,2); pg += __shfl_xor(pg,4);
    if (r==0) gdg[e0+t] += pg;
}

// layer-2 bwd dst pass: Gd[dst] = gH[dst] * sum_e ds
__global__ __launch_bounds__(128) void k_bwd_dst(
    const int* __restrict__ csr, const int* __restrict__ rptr, const int* __restrict__ cnt,
    const float* __restrict__ dgnn, const bf* __restrict__ u, const bf* __restrict__ v,
    const float* __restrict__ wdp, const float* __restrict__ bb,
    const bf* __restrict__ gH, float* __restrict__ Gd)
{
    __shared__ int ss[128]; __shared__ float sd[128];
    int dst = blockIdx.x, k = threadIdx.x;
    int n = cnt[dst], r0 = rptr[dst];
    if (k < n){ int e = csr[r0+k]; ss[k] = e>>4; sd[k] = dgnn[e]; }
    __syncthreads();
    float vk = b2f(v[dst*HID+k]), wd = wdp[k], bk = bb[k];
    float dssum = 0.f;
    for (int j=0;j<n;j++){
        float a = b2f(u[ss[j]*HID+k]) + vk + sd[j]*wd + bk;
        float sg = sigf(a);
        dssum += sg*(1.f + a*(1.f - sg));
    }
    Gd[dst*HID+k] = b2f(gH[dst*HID+k])*dssum;
}

// layer-1 bwd: only gdg
__global__ __launch_bounds__(128) void k_bwd1_src(
    const int* __restrict__ gei, const float* __restrict__ dgnn,
    const bf* __restrict__ u, const bf* __restrict__ v,
    const float* __restrict__ wdp, const float* __restrict__ bb,
    const bf* __restrict__ gH, float* __restrict__ gdg)
{
    __shared__ float sQ[16][130];
    int s = blockIdx.x, k = threadIdx.x;
    float uk = b2f(u[s*HID+k]), wd = wdp[k], bk = bb[k];
    int e0 = s*16;
    int dsts[16]; float dv[16];
#pragma unroll
    for (int t=0;t<16;t++){ dsts[t]=gei[EGNN+e0+t]; dv[t]=dgnn[e0+t]; }
#pragma unroll 4
    for (int t=0;t<16;t++){
        float a = uk + b2f(v[dsts[t]*HID+k]) + dv[t]*wd + bk;
        float sg = sigf(a);
        float ds = sg*(1.f + a*(1.f - sg));
        float ga = b2f(gH[dsts[t]*HID+k])*ds;
        sQ[t][k] = ga*wd;
    }
    __syncthreads();
    int t = k >> 3, r = k & 7;
    float pg = 0.f;
#pragma unroll
    for (int i=0;i<16;i++) pg += sQ[t][i + 16*r];
    pg += __shfl_xor(pg,1); pg += __shfl_xor(pg,2); pg += __shfl_xor(pg,4);
    if (r==0) gdg[e0+t] += pg;
}

// gx = Gs@Aaᵀ + Gd@Abᵀ ; t = gx*silu'(z) ; gH = t@Cᵀ (bf16 out)
__global__ __launch_bounds__(128) void k_gx_node_bwd(
    const float* __restrict__ Gs, const float* __restrict__ Gd,
    const float* __restrict__ A, const float* __restrict__ z,
    const float* __restrict__ C, bf* __restrict__ gH)
{
    __shared__ float sGs[NPB][HID], sGd[NPB][HID], sh2[NPB][HID];
    int j = threadIdx.x;
    int i0 = blockIdx.x*NPB;
#pragma unroll
    for (int t=0;t<NPB;t++){ sGs[t][j]=Gs[(i0+t)*HID+j]; sGd[t][j]=Gd[(i0+t)*HID+j]; }
    __syncthreads();
    float a[NPB];
#pragma unroll
    for (int t=0;t<NPB;t++) a[t]=0.f;
    const float* ra = A + j*HID;
    const float* rb = A + (HID+j)*HID;
#pragma unroll 4
    for (int k=0;k<HID;k++){
        float wa = ra[k], wb = rb[k];
#pragma unroll
        for (int t=0;t<NPB;t++) a[t] += sGs[t][k]*wa + sGd[t][k]*wb;
    }
#pragma unroll
    for (int t=0;t<NPB;t++){
        float zz = z[(i0+t)*HID+j];
        float sg = sigf(zz);
        sh2[t][j] = a[t]*sg*(1.0f+zz*(1.0f-sg));
    }
    __syncthreads();
    float b[NPB];
#pragma unroll
    for (int t=0;t<NPB;t++) b[t]=0.f;
    const float* rc = C + j*HID;
#pragma unroll 4
    for (int k=0;k<HID;k++){
        float wc = rc[k];
#pragma unroll
        for (int t=0;t<NPB;t++) b[t] += sh2[t][k]*wc;
    }
#pragma unroll
    for (int t=0;t<NPB;t++) gH[(i0+t)*HID+j]=f2b(b[t]);
}

// forces: 8 lanes/atom, outgoing (contiguous) + incoming (CSR), no atomics
__global__ __launch_bounds__(256) void k_force_atom(
    const float* __restrict__ pos, const int* __restrict__ gei,
    const int* __restrict__ csr, const int* __restrict__ rptr, const int* __restrict__ cnt,
    const float* __restrict__ dgnn, const float* __restrict__ gdg,
    float* __restrict__ grad)
{
    int T = blockIdx.x*256 + threadIdx.x;
    int i = T >> 3, p = T & 7;
    float px = pos[3*i+0], py = pos[3*i+1], pz = pos[3*i+2];
    float ax=0.f, ay=0.f, az=0.f;
    for (int j=p;j<16;j+=8){
        int e = i*16 + j;
        int o = gei[EGNN+e];
        float c = gdg[e]/dgnn[e];
        ax += c*(px - pos[3*o+0]);
        ay += c*(py - pos[3*o+1]);
        az += c*(pz - pos[3*o+2]);
    }
    int n = cnt[i], r0 = rptr[i];
    for (int j=p;j<n;j+=8){
        int e = csr[r0+j];
        int o = e >> 4;
        float c = gdg[e]/dgnn[e];
        ax += c*(px - pos[3*o+0]);
        ay += c*(py - pos[3*o+1]);
        az += c*(pz - pos[3*o+2]);
    }
    ax += __shfl_xor(ax,1); ax += __shfl_xor(ax,2); ax += __shfl_xor(ax,4);
    ay += __shfl_xor(ay,1); ay += __shfl_xor(ay,2); ay += __shfl_xor(ay,4);
    az += __shfl_xor(az,1); az += __shfl_xor(az,2); az += __shfl_xor(az,4);
    if (p==0){
        grad[3*i+0] += ax;
        grad[3*i+1] += ay;
        grad[3*i+2] += az;
    }
}

__global__ __launch_bounds__(256) void k_final(
    const float* __restrict__ egb, const float* __restrict__ x3,
    const float* __restrict__ grad, float* __restrict__ out)
{
    __shared__ float red[4];
    int m = blockIdx.x, tid = threadIdx.x;
    int i = m*ATOMSM + tid;
    float en = egb[i] + x3[i];
    float v = waveRed(en);
    int wave = tid>>6, lane = tid&63;
    if (lane==0) red[wave] = v;
    __syncthreads();
    if (tid==0) out[m] = red[0]+red[1]+red[2]+red[3];
    float* f = out + MOLS;
    f[3*i+0] = -grad[3*i+0];
    f[3*i+1] = -grad[3*i+1];
    f[3*i+2] = -grad[3*i+2];
}

extern "C" void kernel_launch(void* const* d_in, const int* in_sizes, int n_in,
                              void* d_out, int out_size, void* d_ws, size_t ws_size,
                              hipStream_t stream)
{
    const float* pos  = (const float*)d_in[0];
    const float* feat = (const float*)d_in[1];
    const int* ei  = (const int*)d_in[3];
    const int* gei = (const int*)d_in[4];
    const float* A1f = (const float*)d_in[5];  const float* B1f = (const float*)d_in[6];
    const float* C1f = (const float*)d_in[7];  const float* D1f = (const float*)d_in[8];
    const float* A2f = (const float*)d_in[9];  const float* B2f = (const float*)d_in[10];
    const float* C2f = (const float*)d_in[11]; const float* D2f = (const float*)d_in[12];
    const float* A3f = (const float*)d_in[13]; const float* B3f = (const float*)d_in[14];
    const float* C3f = (const float*)d_in[15]; const float* D3f = (const float*)d_in[16];

    float* w = (float*)d_ws;
    size_t off = 0;
    auto nxt = [&](size_t n)->float*{ float* p = w + off; off += (n + 255) & ~(size_t)255; return p; };
    float* Isum = nxt(NATOMS); float* Bv = nxt(NATOMS); float* cB = nxt(NATOMS);
    float* gB = nxt(NATOMS); float* egb = nxt(NATOMS); float* x3 = nxt(NATOMS);
    int*   cnt  = (int*)nxt(NATOMS);
    int*   rptr = (int*)nxt(NATOMS);
    int*   curs = (int*)nxt(NATOMS);
    int*   csr  = (int*)nxt(EGNN);
    float* dgnn = nxt(EGNN); float* gdgnn = nxt(EGNN); float* gdgb = nxt(EGB);
    float* grad = nxt(3*NATOMS);
    float* z1 = nxt(NH); float* z2 = nxt(NH);
    float* Hs1 = nxt(NH); float* Hs2 = nxt(NH);
    float* Gs3 = nxt(NH); float* Gd3 = nxt(NH);
    bf* u1 = (bf*)nxt(NH/2); bf* v1 = (bf*)nxt(NH/2);
    bf* u2 = (bf*)nxt(NH/2); bf* v2 = (bf*)nxt(NH/2);
    bf* v3 = (bf*)nxt(NH/2);
    // aliases (lifetimes):
    bf* u3  = (bf*)Hs1;   // Hs1 dead after node_fwd_uv #1
    bf* gH2 = (bf*)Hs2;   // Hs2 dead after node_fwd_uv #2
    float* Gs2 = Gs3;     // dead after gx_node_bwd(3->2)
    float* Gd2 = Gd3;
    bf* gH1 = u3;         // u3 dead after l3_src/l3_dst

    hipMemsetAsync(Isum, 0, NATOMS*sizeof(float), stream);
    hipMemsetAsync(cnt,  0, NATOMS*sizeof(int), stream);
    hipMemsetAsync(grad, 0, 3*NATOMS*sizeof(float), stream);

    // GB chain
    k_gbA<<<EGB/256,256,0,stream>>>(pos, feat, ei, Isum);
    k_gbB<<<NATOMS/256,256,0,stream>>>(feat, Isum, Bv, cB, gB, egb);
    k_gbC<<<NATOMS*8/256,256,0,stream>>>(pos, feat, ei, Bv, egb, gdgb, gB);
    k_gbD<<<NATOMS/256,256,0,stream>>>(gB, cB);
    k_gbE<<<NATOMS*8/256,256,0,stream>>>(pos, feat, ei, cB, gdgb, grad);

    // dist + CSR build
    k_dist<<<EGNN/256,256,0,stream>>>(pos, gei, dgnn, cnt);
    k_scan<<<MOLS,256,0,stream>>>(cnt, rptr, curs);
    k_fill<<<EGNN/256,256,0,stream>>>(gei, curs, csr);

    // forward
    k_uv1<<<NH/256,256,0,stream>>>(feat, A1f, u1, v1);
    k_edge_fwd_dst<<<NATOMS,128,0,stream>>>(csr, rptr, cnt, dgnn, u1, v1, A1f+4*HID, B1f, Hs1);
    k_node_fwd_uv<<<NATOMS/NPB,128,0,stream>>>(Hs1, cnt, C1f, D1f, A2f, z1, u2, v2);
    k_edge_fwd_dst<<<NATOMS,128,0,stream>>>(csr, rptr, cnt, dgnn, u2, v2, A2f+256*HID, B2f, Hs2);
    k_node_fwd_uv<<<NATOMS/NPB,128,0,stream>>>(Hs2, cnt, C2f, D2f, A3f, z2, u3, v3);

    // layer-3 fwd+bwd (split src/dst)
    k_l3_src<<<NATOMS,128,0,stream>>>(gei, dgnn, u3, v3, A3f, B3f, C3f, Gs3, gdgnn);
    k_l3_dst<<<NATOMS,128,0,stream>>>(csr, rptr, cnt, dgnn, u3, v3, A3f, B3f, C3f, D3f, Gd3, x3);

    // backward chain
    k_gx_node_bwd<<<NATOMS/NPB,128,0,stream>>>(Gs3, Gd3, A3f, z2, C2f, gH2);
    k_bwd_src<<<NATOMS,128,0,stream>>>(gei, dgnn, u2, v2, A2f+256*HID, B2f, gH2, Gs2, gdgnn);
    k_bwd_dst<<<NATOMS,128,0,stream>>>(csr, rptr, cnt, dgnn, u2, v2, A2f+256*HID, B2f, gH2, Gd2);
    k_gx_node_bwd<<<NATOMS/NPB,128,0,stream>>>(Gs2, Gd2, A2f, z1, C1f, gH1);
    k_bwd1_src<<<NATOMS,128,0,stream>>>(gei, dgnn, u1, v1, A1f+4*HID, B1f, gH1, gdgnn);
    k_force_atom<<<NATOMS*8/256,256,0,stream>>>(pos, gei, csr, rptr, cnt, dgnn, gdgnn, grad);

    k_final<<<MOLS,256,0,stream>>>(egb, x3, grad, (float*)d_out);
}

// Round 8
// 510.680 us; speedup vs baseline: 7.6012x; 1.1915x over previous
//
#include <hip/hip_runtime.h>
#include <hip/hip_bf16.h>

#define NATOMS 16384
#define MOLS   64
#define ATOMSM 256
#define EGB    524288
#define EGNN   262144
#define HID    128
#define NH     (NATOMS*HID)

#define OFFSETC 0.009f
#define ALPHAC  1.0f
#define BETAC   0.8f
#define GAMMAC  4.85f
#define PREFC   (-138.935456f*(1.0f-1.0f/78.5f))

typedef __hip_bfloat16 bf;
typedef __attribute__((ext_vector_type(8))) short bf8v;   // 8 bf16 (4 VGPRs)
typedef __attribute__((ext_vector_type(4))) float f4v;    // MFMA acc

__device__ __forceinline__ float b2f(bf x){ return __bfloat162float(x); }
__device__ __forceinline__ bf f2b(float x){ return __float2bfloat16(x); }
__device__ __forceinline__ short f2s(float x){ bf h = f2b(x); return *(short*)&h; }
__device__ __forceinline__ float sigf(float x){ return 1.0f/(1.0f+__expf(-x)); }
__device__ __forceinline__ float waveRed(float v){
    v += __shfl_xor(v,32); v += __shfl_xor(v,16); v += __shfl_xor(v,8);
    v += __shfl_xor(v,4);  v += __shfl_xor(v,2);  v += __shfl_xor(v,1);
    return v;
}
__device__ __forceinline__ bf8v pack8(const float* p){
    float4 f0 = *(const float4*)p;
    float4 f1 = *(const float4*)(p+4);
    bf8v r;
    r[0]=f2s(f0.x); r[1]=f2s(f0.y); r[2]=f2s(f0.z); r[3]=f2s(f0.w);
    r[4]=f2s(f1.x); r[5]=f2s(f1.y); r[6]=f2s(f1.z); r[7]=f2s(f1.w);
    return r;
}

// ---------------- GB part (round-5 proven) ----------------
__global__ __launch_bounds__(256) void k_gbA(
    const float* __restrict__ pos, const float* __restrict__ feat,
    const int* __restrict__ ei, float* __restrict__ Isum)
{
    int e = blockIdx.x*256 + threadIdx.x;
    if (e >= EGB) return;
    int s = e >> 5;
    int dd = ei[EGB+e];
    float dx = pos[3*s+0] - pos[3*dd+0];
    float dy = pos[3*s+1] - pos[3*dd+1];
    float dz = pos[3*s+2] - pos[3*dd+2];
    float d  = sqrtf(dx*dx+dy*dy+dz*dz + 1e-12f);
    float sr = feat[7*s+2] * (feat[7*s+1] - OFFSETC);
    float rho_i = feat[7*dd+1] - OFFSETC;
    float U = d + sr;
    if (rho_i < U){
        float L = fmaxf(rho_i, fabsf(d - sr));
        float invU = 1.0f/U, invL = 1.0f/L;
        float I = 0.5f*invL - 0.5f*invU
                + 0.125f*(d - sr*sr/d)*(invU*invU - invL*invL)
                + 0.25f*__logf(L*invU)/d;
        atomicAdd(&Isum[dd], I);
    }
}

__global__ __launch_bounds__(256) void k_gbB(
    const float* __restrict__ feat, const float* __restrict__ Isum,
    float* __restrict__ Bv, float* __restrict__ cB, float* __restrict__ gB,
    float* __restrict__ egb)
{
    int i = blockIdx.x*256 + threadIdx.x;
    if (i >= NATOMS) return;
    float q   = feat[7*i+0];
    float rad = feat[7*i+1];
    float rho = rad - OFFSETC;
    float psi = Isum[i]*rho;
    float u = psi*(ALPHAC + psi*(-BETAC + GAMMAC*psi));
    float t = tanhf(u);
    float B = 1.0f/(1.0f/rho - t/rad);
    Bv[i] = B;
    float du = ALPHAC + psi*(-2.0f*BETAC + 3.0f*GAMMAC*psi);
    cB[i] = B*B*((1.0f-t*t)/rad)*du*rho;
    float Cs = 0.5f*PREFC*q*q;
    egb[i] = Cs/B;
    gB[i]  = -Cs/(B*B);
}

__global__ __launch_bounds__(256) void k_gbC(
    const float* __restrict__ pos, const float* __restrict__ feat,
    const int* __restrict__ ei, const float* __restrict__ Bv,
    float* __restrict__ egb, float* __restrict__ gdgb, float* __restrict__ gB)
{
    int T = blockIdx.x*256 + threadIdx.x;
    int s = T >> 3, p = T & 7;
    int e0 = s*32 + p*4;
    float px = pos[3*s+0], py = pos[3*s+1], pz = pos[3*s+2];
    float qs = feat[7*s+0];
    float Bs = Bv[s];
    float gsrc = 0.f;
    const int* dP = ei + EGB;
#pragma unroll
    for (int j=0;j<4;j++){
        int dd = dP[e0+j];
        float dx = px - pos[3*dd+0];
        float dy = py - pos[3*dd+1];
        float dz = pz - pos[3*dd+2];
        float d2 = dx*dx+dy*dy+dz*dz + 1e-12f;
        float d  = sqrtf(d2);
        float Bd = Bv[dd];
        float C = 0.5f*PREFC*feat[7*dd+0]*qs;
        float P = Bd*Bs;
        float ex = __expf(-d2/(4.f*P));
        float f2 = d2 + P*ex;
        float f  = sqrtf(f2);
        atomicAdd(&egb[dd], C/f);
        float f3i = 1.f/(f2*f);
        gdgb[e0+j] = -C*d*(1.f - 0.25f*ex)*f3i;
        float common = -C*ex*(1.f + d2/(4.f*P))*0.5f*f3i;
        atomicAdd(&gB[dd], common*Bs);
        gsrc += common*Bd;
    }
    gsrc += __shfl_xor(gsrc,1);
    gsrc += __shfl_xor(gsrc,2);
    gsrc += __shfl_xor(gsrc,4);
    if (p==0) atomicAdd(&gB[s], gsrc);
}

__global__ __launch_bounds__(256) void k_gbD(
    const float* __restrict__ gB, float* __restrict__ cB)
{
    int i = blockIdx.x*256 + threadIdx.x;
    if (i < NATOMS) cB[i] *= gB[i];
}

__global__ __launch_bounds__(256) void k_gbE(
    const float* __restrict__ pos, const float* __restrict__ feat,
    const int* __restrict__ ei, const float* __restrict__ cBg,
    const float* __restrict__ gdgb, float* __restrict__ grad)
{
    int T = blockIdx.x*256 + threadIdx.x;
    int s = T >> 3, p = T & 7;
    int e0 = s*32 + p*4;
    float px = pos[3*s+0], py = pos[3*s+1], pz = pos[3*s+2];
    float sr = feat[7*s+2] * (feat[7*s+1] - OFFSETC);
    float gx=0.f, gy=0.f, gz=0.f;
    const int* dP = ei + EGB;
#pragma unroll
    for (int j=0;j<4;j++){
        int dd = dP[e0+j];
        float dx = px - pos[3*dd+0];
        float dy = py - pos[3*dd+1];
        float dz = pz - pos[3*dd+2];
        float d2 = dx*dx+dy*dy+dz*dz + 1e-12f;
        float d  = sqrtf(d2);
        float rho_i = feat[7*dd+1] - OFFSETC;
        float U = d + sr;
        float gd = gdgb[e0+j];
        if (rho_i < U){
            float aa = fabsf(d - sr);
            float L, Lp;
            if (rho_i >= aa){ L = rho_i; Lp = 0.f; }
            else { L = aa; Lp = (d >= sr) ? 1.f : -1.f; }
            float invU = 1.f/U, invL = 1.f/L;
            float invU2=invU*invU, invL2=invL*invL;
            float dIdd = -0.5f*Lp*invL2 + 0.5f*invU2
                + 0.125f*(1.f + sr*sr/d2)*(invU2 - invL2)
                + 0.125f*(d - sr*sr/d)*(2.f*Lp*invL2*invL - 2.f*invU2*invU)
                + 0.25f*((Lp*invL - invU)/d - __logf(L*invU)/d2);
            gd += cBg[dd]*dIdd;
        }
        float c = gd/d;
        gx += c*dx; gy += c*dy; gz += c*dz;
        atomicAdd(&grad[3*dd+0], -c*dx);
        atomicAdd(&grad[3*dd+1], -c*dy);
        atomicAdd(&grad[3*dd+2], -c*dz);
    }
    gx += __shfl_xor(gx,1); gx += __shfl_xor(gx,2); gx += __shfl_xor(gx,4);
    gy += __shfl_xor(gy,1); gy += __shfl_xor(gy,2); gy += __shfl_xor(gy,4);
    gz += __shfl_xor(gz,1); gz += __shfl_xor(gz,2); gz += __shfl_xor(gz,4);
    if (p==0){
        atomicAdd(&grad[3*s+0], gx);
        atomicAdd(&grad[3*s+1], gy);
        atomicAdd(&grad[3*s+2], gz);
    }
}

// ---------------- GNN: dist + CSR build ----------------
__global__ __launch_bounds__(256) void k_dist(
    const float* __restrict__ pos, const int* __restrict__ gei,
    float* __restrict__ dgnn, int* __restrict__ cnt)
{
    int e = blockIdx.x*256 + threadIdx.x;
    if (e >= EGNN) return;
    int s = gei[e], dd = gei[EGNN+e];
    float dx = pos[3*s+0] - pos[3*dd+0];
    float dy = pos[3*s+1] - pos[3*dd+1];
    float dz = pos[3*s+2] - pos[3*dd+2];
    dgnn[e] = sqrtf(dx*dx+dy*dy+dz*dz + 1e-12f);
    atomicAdd(&cnt[dd], 1);
}

__global__ __launch_bounds__(256) void k_scan(
    const int* __restrict__ cnt, int* __restrict__ rptr, int* __restrict__ cursor)
{
    __shared__ int sc[256];
    int m = blockIdx.x, t = threadIdx.x;
    int c = cnt[m*256+t];
    sc[t] = c; __syncthreads();
    for (int off=1; off<256; off<<=1){
        int x = (t>=off) ? sc[t-off] : 0;
        __syncthreads();
        sc[t] += x;
        __syncthreads();
    }
    int ex = m*4096 + sc[t] - c;
    rptr[m*256+t] = ex;
    cursor[m*256+t] = ex;
}

__global__ __launch_bounds__(256) void k_fill(
    const int* __restrict__ gei, int* __restrict__ cursor, int* __restrict__ csr)
{
    int e = blockIdx.x*256 + threadIdx.x;
    if (e >= EGNN) return;
    int dst = gei[EGNN+e];
    int pos = atomicAdd(&cursor[dst], 1);
    csr[pos] = e;
}

// ---------------- weight prep: bf16 raw + transposed layouts ----------------
__global__ __launch_bounds__(256) void k_wprep(
    const float* __restrict__ A2, const float* __restrict__ C1,
    const float* __restrict__ A3, const float* __restrict__ C2,
    short* __restrict__ C1t, short* __restrict__ C2t,
    short* __restrict__ A2at, short* __restrict__ A2bt,
    short* __restrict__ A3at, short* __restrict__ A3bt,
    short* __restrict__ rA2a, short* __restrict__ rA2b,
    short* __restrict__ rA3a, short* __restrict__ rA3b,
    short* __restrict__ rC1, short* __restrict__ rC2)
{
    int gid = blockIdx.x*256 + threadIdx.x;   // [j][k], j=gid>>7, k=gid&127
    int j = gid >> 7, k = gid & 127;
    C1t[gid]  = f2s(C1[k*HID+j]);
    C2t[gid]  = f2s(C2[k*HID+j]);
    A2at[gid] = f2s(A2[k*HID+j]);
    A2bt[gid] = f2s(A2[(HID+k)*HID+j]);
    A3at[gid] = f2s(A3[k*HID+j]);
    A3bt[gid] = f2s(A3[(HID+k)*HID+j]);
    rA2a[gid] = f2s(A2[gid]);
    rA2b[gid] = f2s(A2[HID*HID+gid]);
    rA3a[gid] = f2s(A3[gid]);
    rA3b[gid] = f2s(A3[HID*HID+gid]);
    rC1[gid]  = f2s(C1[gid]);
    rC2[gid]  = f2s(C2[gid]);
}

// ---------------- GNN compute ----------------
__global__ __launch_bounds__(256) void k_uv1(
    const float* __restrict__ feat, const float* __restrict__ A1,
    bf* __restrict__ u1, bf* __restrict__ v1)
{
    int gid = blockIdx.x*256 + threadIdx.x;
    int i = gid >> 7, k = gid & 127;
    float q = feat[7*i+0], r = feat[7*i+1];
    u1[gid] = f2b(q*A1[k]       + r*A1[HID+k]);
    v1[gid] = f2b(q*A1[2*HID+k] + r*A1[3*HID+k]);
}

__global__ __launch_bounds__(128) void k_edge_fwd_dst(
    const int* __restrict__ csr, const int* __restrict__ rptr, const int* __restrict__ cnt,
    const float* __restrict__ dgnn, const bf* __restrict__ u, const bf* __restrict__ v,
    const float* __restrict__ wdp, const float* __restrict__ bb,
    float* __restrict__ Hs)
{
    __shared__ int ss[128]; __shared__ float sd[128];
    int dst = blockIdx.x, k = threadIdx.x;
    int n = cnt[dst], r0 = rptr[dst];
    if (k < n){ int e = csr[r0+k]; ss[k] = e>>4; sd[k] = dgnn[e]; }
    __syncthreads();
    float vk = b2f(v[dst*HID+k]), wd = wdp[k], bk = bb[k];
    float hsum = 0.f;
    for (int j=0;j<n;j++){
        float a = b2f(u[ss[j]*HID+k]) + vk + sd[j]*wd + bk;
        hsum += a*sigf(a);
    }
    Hs[dst*HID+k] = hsum;
}

// MFMA node forward: z = Hs@C + cnt*D ; x=silu(z) ; u=x@Aa ; v=x@Ab
__global__ __launch_bounds__(256) void k_node_fwd_uv_mfma(
    const float* __restrict__ Hs, const int* __restrict__ cnt,
    const short* __restrict__ Ct, const float* __restrict__ D,
    const short* __restrict__ Aat, const short* __restrict__ Abt,
    float* __restrict__ z, bf* __restrict__ u, bf* __restrict__ v)
{
    __shared__ short sx[64*HID];
    int lane = threadIdx.x & 63, w = threadIdx.x >> 6;
    int m0 = blockIdx.x*64 + w*16;
    int ar = lane & 15, kg = lane >> 4;
    bf8v af[4];
#pragma unroll
    for (int s=0;s<4;s++) af[s] = pack8(Hs + (size_t)(m0+ar)*HID + s*32 + kg*8);
    f4v acc[8];
#pragma unroll
    for (int nt=0;nt<8;nt++){
        acc[nt] = (f4v){0.f,0.f,0.f,0.f};
        const short* bp = Ct + (nt*16+ar)*HID + kg*8;
#pragma unroll
        for (int s=0;s<4;s++){
            bf8v bv = *(const bf8v*)(bp + s*32);
            acc[nt] = __builtin_amdgcn_mfma_f32_16x16x32_bf16(af[s], bv, acc[nt], 0,0,0);
        }
    }
    float cn[4];
#pragma unroll
    for (int r=0;r<4;r++) cn[r] = (float)cnt[m0 + kg*4 + r];
#pragma unroll
    for (int nt=0;nt<8;nt++){
        int j = nt*16 + ar;
        float Dj = D[j];
#pragma unroll
        for (int r=0;r<4;r++){
            int m = m0 + kg*4 + r;
            float zv = acc[nt][r] + cn[r]*Dj;
            z[(size_t)m*HID + j] = zv;
            float xv = zv*sigf(zv);
            sx[(w*16 + kg*4 + r)*HID + j] = f2s(xv);
        }
    }
    __syncthreads();
#pragma unroll
    for (int s=0;s<4;s++) af[s] = *(const bf8v*)&sx[(w*16+ar)*HID + s*32 + kg*8];
    f4v au[8], av[8];
#pragma unroll
    for (int nt=0;nt<8;nt++){
        au[nt] = (f4v){0.f,0.f,0.f,0.f};
        av[nt] = (f4v){0.f,0.f,0.f,0.f};
        const short* bpa = Aat + (nt*16+ar)*HID + kg*8;
        const short* bpb = Abt + (nt*16+ar)*HID + kg*8;
#pragma unroll
        for (int s=0;s<4;s++){
            bf8v ba = *(const bf8v*)(bpa + s*32);
            bf8v bb = *(const bf8v*)(bpb + s*32);
            au[nt] = __builtin_amdgcn_mfma_f32_16x16x32_bf16(af[s], ba, au[nt], 0,0,0);
            av[nt] = __builtin_amdgcn_mfma_f32_16x16x32_bf16(af[s], bb, av[nt], 0,0,0);
        }
    }
#pragma unroll
    for (int nt=0;nt<8;nt++){
        int j = nt*16 + ar;
#pragma unroll
        for (int r=0;r<4;r++){
            int m = m0 + kg*4 + r;
            u[(size_t)m*HID + j] = f2b(au[nt][r]);
            v[(size_t)m*HID + j] = f2b(av[nt][r]);
        }
    }
}

// MFMA node backward: gx = Gs@Aaᵀ + Gd@Abᵀ ; t = gx*silu'(z) ; gH = t@Cᵀ
__global__ __launch_bounds__(256) void k_gx_node_bwd_mfma(
    const float* __restrict__ Gs, const float* __restrict__ Gd,
    const short* __restrict__ Ra, const short* __restrict__ Rb,
    const float* __restrict__ z, const short* __restrict__ Rc,
    bf* __restrict__ gH)
{
    __shared__ short st[64*HID];
    int lane = threadIdx.x & 63, w = threadIdx.x >> 6;
    int m0 = blockIdx.x*64 + w*16;
    int ar = lane & 15, kg = lane >> 4;
    bf8v as_[4], ad_[4];
#pragma unroll
    for (int s=0;s<4;s++){
        as_[s] = pack8(Gs + (size_t)(m0+ar)*HID + s*32 + kg*8);
        ad_[s] = pack8(Gd + (size_t)(m0+ar)*HID + s*32 + kg*8);
    }
    f4v acc[8];
#pragma unroll
    for (int nt=0;nt<8;nt++){
        acc[nt] = (f4v){0.f,0.f,0.f,0.f};
        const short* bpa = Ra + (nt*16+ar)*HID + kg*8;
        const short* bpb = Rb + (nt*16+ar)*HID + kg*8;
#pragma unroll
        for (int s=0;s<4;s++){
            bf8v ba = *(const bf8v*)(bpa + s*32);
            bf8v bb = *(const bf8v*)(bpb + s*32);
            acc[nt] = __builtin_amdgcn_mfma_f32_16x16x32_bf16(as_[s], ba, acc[nt], 0,0,0);
            acc[nt] = __builtin_amdgcn_mfma_f32_16x16x32_bf16(ad_[s], bb, acc[nt], 0,0,0);
        }
    }
#pragma unroll
    for (int nt=0;nt<8;nt++){
        int j = nt*16 + ar;
#pragma unroll
        for (int r=0;r<4;r++){
            int m = m0 + kg*4 + r;
            float zz = z[(size_t)m*HID + j];
            float sg = sigf(zz);
            float t = acc[nt][r]*sg*(1.f + zz*(1.f - sg));
            st[(w*16 + kg*4 + r)*HID + j] = f2s(t);
        }
    }
    __syncthreads();
    bf8v af[4];
#pragma unroll
    for (int s=0;s<4;s++) af[s] = *(const bf8v*)&st[(w*16+ar)*HID + s*32 + kg*8];
    f4v a2[8];
#pragma unroll
    for (int nt=0;nt<8;nt++){
        a2[nt] = (f4v){0.f,0.f,0.f,0.f};
        const short* bp = Rc + (nt*16+ar)*HID + kg*8;
#pragma unroll
        for (int s=0;s<4;s++){
            bf8v bc = *(const bf8v*)(bp + s*32);
            a2[nt] = __builtin_amdgcn_mfma_f32_16x16x32_bf16(af[s], bc, a2[nt], 0,0,0);
        }
    }
#pragma unroll
    for (int nt=0;nt<8;nt++){
        int j = nt*16 + ar;
#pragma unroll
        for (int r=0;r<4;r++){
            gH[(size_t)(m0 + kg*4 + r)*HID + j] = f2b(a2[nt][r]);
        }
    }
}

// l3 src pass: Gs (plain) + gdg (plain)
__global__ __launch_bounds__(128) void k_l3_src(
    const int* __restrict__ gei, const float* __restrict__ dgnn,
    const bf* __restrict__ u, const bf* __restrict__ v,
    const float* __restrict__ A3, const float* __restrict__ B3,
    const float* __restrict__ C3,
    float* __restrict__ Gs, float* __restrict__ gdg)
{
    __shared__ float sQ[16][130];
    int s = blockIdx.x, k = threadIdx.x;
    float uk = b2f(u[s*HID+k]), wd = A3[256*HID+k], bk = B3[k], ck = C3[k];
    int e0 = s*16;
    int dsts[16]; float dv[16];
#pragma unroll
    for (int t=0;t<16;t++){ dsts[t]=gei[EGNN+e0+t]; dv[t]=dgnn[e0+t]; }
    float gs = 0.f;
#pragma unroll 4
    for (int t=0;t<16;t++){
        float a = uk + b2f(v[dsts[t]*HID+k]) + dv[t]*wd + bk;
        float sg = sigf(a);
        float ds = sg*(1.f + a*(1.f - sg));
        float ga = ck*ds;
        gs += ga;
        sQ[t][k] = ga*wd;
    }
    Gs[s*HID+k] = gs;
    __syncthreads();
    int t = k >> 3, r = k & 7;
    float pg = 0.f;
#pragma unroll
    for (int i=0;i<16;i++) pg += sQ[t][i + 16*r];
    pg += __shfl_xor(pg,1); pg += __shfl_xor(pg,2); pg += __shfl_xor(pg,4);
    if (r==0) gdg[e0+t] = pg;
}

// l3 dst pass: Gd (plain) + x3 (plain)
__global__ __launch_bounds__(128) void k_l3_dst(
    const int* __restrict__ csr, const int* __restrict__ rptr, const int* __restrict__ cnt,
    const float* __restrict__ dgnn, const bf* __restrict__ u, const bf* __restrict__ v,
    const float* __restrict__ A3, const float* __restrict__ B3,
    const float* __restrict__ C3, const float* __restrict__ D3,
    float* __restrict__ Gd, float* __restrict__ x3)
{
    __shared__ int ss[128]; __shared__ float sd[128]; __shared__ float rr[2];
    int dst = blockIdx.x, k = threadIdx.x;
    int n = cnt[dst], r0 = rptr[dst];
    if (k < n){ int e = csr[r0+k]; ss[k] = e>>4; sd[k] = dgnn[e]; }
    __syncthreads();
    float vk = b2f(v[dst*HID+k]), wd = A3[256*HID+k], bk = B3[k], ck = C3[k];
    float hsum = 0.f, dssum = 0.f;
    for (int j=0;j<n;j++){
        float a = b2f(u[ss[j]*HID+k]) + vk + sd[j]*wd + bk;
        float sg = sigf(a);
        hsum += a*sg;
        dssum += sg*(1.f + a*(1.f - sg));
    }
    Gd[dst*HID+k] = ck*dssum;
    float pv = waveRed(ck*hsum);
    if ((k&63)==0) rr[k>>6] = pv;
    __syncthreads();
    if (k==0) x3[dst] = rr[0] + rr[1] + (float)n*D3[0];
}

__global__ __launch_bounds__(128) void k_bwd_src(
    const int* __restrict__ gei, const float* __restrict__ dgnn,
    const bf* __restrict__ u, const bf* __restrict__ v,
    const float* __restrict__ wdp, const float* __restrict__ bb,
    const bf* __restrict__ gH,
    float* __restrict__ Gs, float* __restrict__ gdg)
{
    __shared__ float sQ[16][130];
    int s = blockIdx.x, k = threadIdx.x;
    float uk = b2f(u[s*HID+k]), wd = wdp[k], bk = bb[k];
    int e0 = s*16;
    int dsts[16]; float dv[16];
#pragma unroll
    for (int t=0;t<16;t++){ dsts[t]=gei[EGNN+e0+t]; dv[t]=dgnn[e0+t]; }
    float gs = 0.f;
#pragma unroll 4
    for (int t=0;t<16;t++){
        float a = uk + b2f(v[dsts[t]*HID+k]) + dv[t]*wd + bk;
        float sg = sigf(a);
        float ds = sg*(1.f + a*(1.f - sg));
        float ga = b2f(gH[dsts[t]*HID+k])*ds;
        gs += ga;
        sQ[t][k] = ga*wd;
    }
    Gs[s*HID+k] = gs;
    __syncthreads();
    int t = k >> 3, r = k & 7;
    float pg = 0.f;
#pragma unroll
    for (int i=0;i<16;i++) pg += sQ[t][i + 16*r];
    pg += __shfl_xor(pg,1); pg += __shfl_xor(pg,2); pg += __shfl_xor(pg,4);
    if (r==0) gdg[e0+t] += pg;
}

__global__ __launch_bounds__(128) void k_bwd_dst(
    const int* __restrict__ csr, const int* __restrict__ rptr, const int* __restrict__ cnt,
    const float* __restrict__ dgnn, const bf* __restrict__ u, const bf* __restrict__ v,
    const float* __restrict__ wdp, const float* __restrict__ bb,
    const bf* __restrict__ gH, float* __restrict__ Gd)
{
    __shared__ int ss[128]; __shared__ float sd[128];
    int dst = blockIdx.x, k = threadIdx.x;
    int n = cnt[dst], r0 = rptr[dst];
    if (k < n){ int e = csr[r0+k]; ss[k] = e>>4; sd[k] = dgnn[e]; }
    __syncthreads();
    float vk = b2f(v[dst*HID+k]), wd = wdp[k], bk = bb[k];
    float dssum = 0.f;
    for (int j=0;j<n;j++){
        float a = b2f(u[ss[j]*HID+k]) + vk + sd[j]*wd + bk;
        float sg = sigf(a);
        dssum += sg*(1.f + a*(1.f - sg));
    }
    Gd[dst*HID+k] = b2f(gH[dst*HID+k])*dssum;
}

__global__ __launch_bounds__(128) void k_bwd1_src(
    const int* __restrict__ gei, const float* __restrict__ dgnn,
    const bf* __restrict__ u, const bf* __restrict__ v,
    const float* __restrict__ wdp, const float* __restrict__ bb,
    const bf* __restrict__ gH, float* __restrict__ gdg)
{
    __shared__ float sQ[16][130];
    int s = blockIdx.x, k = threadIdx.x;
    float uk = b2f(u[s*HID+k]), wd = wdp[k], bk = bb[k];
    int e0 = s*16;
    int dsts[16]; float dv[16];
#pragma unroll
    for (int t=0;t<16;t++){ dsts[t]=gei[EGNN+e0+t]; dv[t]=dgnn[e0+t]; }
#pragma unroll 4
    for (int t=0;t<16;t++){
        float a = uk + b2f(v[dsts[t]*HID+k]) + dv[t]*wd + bk;
        float sg = sigf(a);
        float ds = sg*(1.f + a*(1.f - sg));
        float ga = b2f(gH[dsts[t]*HID+k])*ds;
        sQ[t][k] = ga*wd;
    }
    __syncthreads();
    int t = k >> 3, r = k & 7;
    float pg = 0.f;
#pragma unroll
    for (int i=0;i<16;i++) pg += sQ[t][i + 16*r];
    pg += __shfl_xor(pg,1); pg += __shfl_xor(pg,2); pg += __shfl_xor(pg,4);
    if (r==0) gdg[e0+t] += pg;
}

__global__ __launch_bounds__(256) void k_force_atom(
    const float* __restrict__ pos, const int* __restrict__ gei,
    const int* __restrict__ csr, const int* __restrict__ rptr, const int* __restrict__ cnt,
    const float* __restrict__ dgnn, const float* __restrict__ gdg,
    float* __restrict__ grad)
{
    int T = blockIdx.x*256 + threadIdx.x;
    int i = T >> 3, p = T & 7;
    float px = pos[3*i+0], py = pos[3*i+1], pz = pos[3*i+2];
    float ax=0.f, ay=0.f, az=0.f;
    for (int j=p;j<16;j+=8){
        int e = i*16 + j;
        int o = gei[EGNN+e];
        float c = gdg[e]/dgnn[e];
        ax += c*(px - pos[3*o+0]);
        ay += c*(py - pos[3*o+1]);
        az += c*(pz - pos[3*o+2]);
    }
    int n = cnt[i], r0 = rptr[i];
    for (int j=p;j<n;j+=8){
        int e = csr[r0+j];
        int o = e >> 4;
        float c = gdg[e]/dgnn[e];
        ax += c*(px - pos[3*o+0]);
        ay += c*(py - pos[3*o+1]);
        az += c*(pz - pos[3*o+2]);
    }
    ax += __shfl_xor(ax,1); ax += __shfl_xor(ax,2); ax += __shfl_xor(ax,4);
    ay += __shfl_xor(ay,1); ay += __shfl_xor(ay,2); ay += __shfl_xor(ay,4);
    az += __shfl_xor(az,1); az += __shfl_xor(az,2); az += __shfl_xor(az,4);
    if (p==0){
        grad[3*i+0] += ax;
        grad[3*i+1] += ay;
        grad[3*i+2] += az;
    }
}

__global__ __launch_bounds__(256) void k_final(
    const float* __restrict__ egb, const float* __restrict__ x3,
    const float* __restrict__ grad, float* __restrict__ out)
{
    __shared__ float red[4];
    int m = blockIdx.x, tid = threadIdx.x;
    int i = m*ATOMSM + tid;
    float en = egb[i] + x3[i];
    float v = waveRed(en);
    int wave = tid>>6, lane = tid&63;
    if (lane==0) red[wave] = v;
    __syncthreads();
    if (tid==0) out[m] = red[0]+red[1]+red[2]+red[3];
    float* f = out + MOLS;
    f[3*i+0] = -grad[3*i+0];
    f[3*i+1] = -grad[3*i+1];
    f[3*i+2] = -grad[3*i+2];
}

extern "C" void kernel_launch(void* const* d_in, const int* in_sizes, int n_in,
                              void* d_out, int out_size, void* d_ws, size_t ws_size,
                              hipStream_t stream)
{
    const float* pos  = (const float*)d_in[0];
    const float* feat = (const float*)d_in[1];
    const int* ei  = (const int*)d_in[3];
    const int* gei = (const int*)d_in[4];
    const float* A1f = (const float*)d_in[5];  const float* B1f = (const float*)d_in[6];
    const float* C1f = (const float*)d_in[7];  const float* D1f = (const float*)d_in[8];
    const float* A2f = (const float*)d_in[9];  const float* B2f = (const float*)d_in[10];
    const float* C2f = (const float*)d_in[11]; const float* D2f = (const float*)d_in[12];
    const float* A3f = (const float*)d_in[13]; const float* B3f = (const float*)d_in[14];
    const float* C3f = (const float*)d_in[15]; const float* D3f = (const float*)d_in[16];

    float* w = (float*)d_ws;
    size_t off = 0;
    auto nxt = [&](size_t n)->float*{ float* p = w + off; off += (n + 255) & ~(size_t)255; return p; };
    float* Isum = nxt(NATOMS); float* Bv = nxt(NATOMS); float* cB = nxt(NATOMS);
    float* gB = nxt(NATOMS); float* egb = nxt(NATOMS); float* x3 = nxt(NATOMS);
    int*   cnt  = (int*)nxt(NATOMS);
    int*   rptr = (int*)nxt(NATOMS);
    int*   curs = (int*)nxt(NATOMS);
    int*   csr  = (int*)nxt(EGNN);
    float* dgnn = nxt(EGNN); float* gdgnn = nxt(EGNN); float* gdgb = nxt(EGB);
    float* grad = nxt(3*NATOMS);
    float* z1 = nxt(NH); float* z2 = nxt(NH);
    float* Hs1 = nxt(NH); float* Hs2 = nxt(NH);
    float* Gs3 = nxt(NH); float* Gd3 = nxt(NH);
    bf* u1 = (bf*)nxt(NH/2); bf* v1 = (bf*)nxt(NH/2);
    bf* u2 = (bf*)nxt(NH/2); bf* v2 = (bf*)nxt(NH/2);
    bf* v3 = (bf*)nxt(NH/2);
    // bf16 weight layouts (each 128x128 shorts = 8192 floats)
    short* C1t  = (short*)nxt(8192); short* C2t  = (short*)nxt(8192);
    short* A2at = (short*)nxt(8192); short* A2bt = (short*)nxt(8192);
    short* A3at = (short*)nxt(8192); short* A3bt = (short*)nxt(8192);
    short* rA2a = (short*)nxt(8192); short* rA2b = (short*)nxt(8192);
    short* rA3a = (short*)nxt(8192); short* rA3b = (short*)nxt(8192);
    short* rC1  = (short*)nxt(8192); short* rC2  = (short*)nxt(8192);
    // aliases (lifetimes):
    bf* u3  = (bf*)Hs1;   // Hs1 dead after node_fwd #1
    bf* gH2 = (bf*)Hs2;   // Hs2 dead after node_fwd #2
    float* Gs2 = Gs3;     // dead after gx_node_bwd(3->2)
    float* Gd2 = Gd3;
    bf* gH1 = u3;         // u3 dead after l3_src/l3_dst

    hipMemsetAsync(Isum, 0, NATOMS*sizeof(float), stream);
    hipMemsetAsync(cnt,  0, NATOMS*sizeof(int), stream);
    hipMemsetAsync(grad, 0, 3*NATOMS*sizeof(float), stream);

    // weight prep (independent of everything else)
    k_wprep<<<64,256,0,stream>>>(A2f, C1f, A3f, C2f,
        C1t, C2t, A2at, A2bt, A3at, A3bt, rA2a, rA2b, rA3a, rA3b, rC1, rC2);

    // GB chain
    k_gbA<<<EGB/256,256,0,stream>>>(pos, feat, ei, Isum);
    k_gbB<<<NATOMS/256,256,0,stream>>>(feat, Isum, Bv, cB, gB, egb);
    k_gbC<<<NATOMS*8/256,256,0,stream>>>(pos, feat, ei, Bv, egb, gdgb, gB);
    k_gbD<<<NATOMS/256,256,0,stream>>>(gB, cB);
    k_gbE<<<NATOMS*8/256,256,0,stream>>>(pos, feat, ei, cB, gdgb, grad);

    // dist + CSR build
    k_dist<<<EGNN/256,256,0,stream>>>(pos, gei, dgnn, cnt);
    k_scan<<<MOLS,256,0,stream>>>(cnt, rptr, curs);
    k_fill<<<EGNN/256,256,0,stream>>>(gei, curs, csr);

    // forward
    k_uv1<<<NH/256,256,0,stream>>>(feat, A1f, u1, v1);
    k_edge_fwd_dst<<<NATOMS,128,0,stream>>>(csr, rptr, cnt, dgnn, u1, v1, A1f+4*HID, B1f, Hs1);
    k_node_fwd_uv_mfma<<<NATOMS/64,256,0,stream>>>(Hs1, cnt, C1t, D1f, A2at, A2bt, z1, u2, v2);
    k_edge_fwd_dst<<<NATOMS,128,0,stream>>>(csr, rptr, cnt, dgnn, u2, v2, A2f+256*HID, B2f, Hs2);
    k_node_fwd_uv_mfma<<<NATOMS/64,256,0,stream>>>(Hs2, cnt, C2t, D2f, A3at, A3bt, z2, u3, v3);

    // layer-3 fwd+bwd (split src/dst)
    k_l3_src<<<NATOMS,128,0,stream>>>(gei, dgnn, u3, v3, A3f, B3f, C3f, Gs3, gdgnn);
    k_l3_dst<<<NATOMS,128,0,stream>>>(csr, rptr, cnt, dgnn, u3, v3, A3f, B3f, C3f, D3f, Gd3, x3);

    // backward chain
    k_gx_node_bwd_mfma<<<NATOMS/64,256,0,stream>>>(Gs3, Gd3, rA3a, rA3b, z2, rC2, gH2);
    k_bwd_src<<<NATOMS,128,0,stream>>>(gei, dgnn, u2, v2, A2f+256*HID, B2f, gH2, Gs2, gdgnn);
    k_bwd_dst<<<NATOMS,128,0,stream>>>(csr, rptr, cnt, dgnn, u2, v2, A2f+256*HID, B2f, gH2, Gd2);
    k_gx_node_bwd_mfma<<<NATOMS/64,256,0,stream>>>(Gs2, Gd2, rA2a, rA2b, z1, rC1, gH1);
    k_bwd1_src<<<NATOMS,128,0,stream>>>(gei, dgnn, u1, v1, A1f+4*HID, B1f, gH1, gdgnn);
    k_force_atom<<<NATOMS*8/256,256,0,stream>>>(pos, gei, csr, rptr, cnt, dgnn, gdgnn, grad);

    k_final<<<MOLS,256,0,stream>>>(egb, x3, grad, (float*)d_out);
}

// Round 9
// 432.880 us; speedup vs baseline: 8.9674x; 1.1797x over previous
//
#include <hip/hip_runtime.h>
#include <hip/hip_bf16.h>

#define NATOMS 16384
#define MOLS   64
#define ATOMSM 256
#define EGB    524288
#define EGNN   262144
#define HID    128
#define NH     (NATOMS*HID)

#define OFFSETC 0.009f
#define ALPHAC  1.0f
#define BETAC   0.8f
#define GAMMAC  4.85f
#define PREFC   (-138.935456f*(1.0f-1.0f/78.5f))

typedef __hip_bfloat16 bf;
typedef __attribute__((ext_vector_type(8))) short bf8v;
typedef __attribute__((ext_vector_type(4))) float f4v;

__device__ __forceinline__ float b2f(bf x){ return __bfloat162float(x); }
__device__ __forceinline__ bf f2b(float x){ return __float2bfloat16(x); }
__device__ __forceinline__ short f2s(float x){ bf h = f2b(x); return *(short*)&h; }
__device__ __forceinline__ float sigf(float x){ return 1.0f/(1.0f+__expf(-x)); }
__device__ __forceinline__ float waveRed(float v){
    v += __shfl_xor(v,32); v += __shfl_xor(v,16); v += __shfl_xor(v,8);
    v += __shfl_xor(v,4);  v += __shfl_xor(v,2);  v += __shfl_xor(v,1);
    return v;
}
__device__ __forceinline__ bf8v pack8(const float* p){
    float4 f0 = *(const float4*)p;
    float4 f1 = *(const float4*)(p+4);
    bf8v r;
    r[0]=f2s(f0.x); r[1]=f2s(f0.y); r[2]=f2s(f0.z); r[3]=f2s(f0.w);
    r[4]=f2s(f1.x); r[5]=f2s(f1.y); r[6]=f2s(f1.z); r[7]=f2s(f1.w);
    return r;
}

// ============ GB: LDS molecule-tile staged (1024 edges/block, 8 blk/mol) ============
__global__ __launch_bounds__(256) void k_gbA(
    const float* __restrict__ pos, const float* __restrict__ feat,
    const int* __restrict__ ei, float* __restrict__ Isum)
{
    __shared__ float sI[256];
    int tid = threadIdx.x;
    sI[tid] = 0.f;
    __syncthreads();
    int T = blockIdx.x*256 + tid;
    int s = T >> 3, p = T & 7;
    int e0 = s*32 + p*4;
    int mbase = (blockIdx.x >> 3) * 256;
    float px = pos[3*s+0], py = pos[3*s+1], pz = pos[3*s+2];
    float sr = feat[7*s+2] * (feat[7*s+1] - OFFSETC);
    const int* dP = ei + EGB;
#pragma unroll
    for (int j=0;j<4;j++){
        int dd = dP[e0+j];
        float dx = px - pos[3*dd+0];
        float dy = py - pos[3*dd+1];
        float dz = pz - pos[3*dd+2];
        float d  = sqrtf(dx*dx+dy*dy+dz*dz + 1e-12f);
        float rho_i = feat[7*dd+1] - OFFSETC;
        float U = d + sr;
        if (rho_i < U){
            float L = fmaxf(rho_i, fabsf(d - sr));
            float invU = 1.0f/U, invL = 1.0f/L;
            float I = 0.5f*invL - 0.5f*invU
                    + 0.125f*(d - sr*sr/d)*(invU*invU - invL*invL)
                    + 0.25f*__logf(L*invU)/d;
            atomicAdd(&sI[dd & 255], I);
        }
    }
    __syncthreads();
    atomicAdd(&Isum[mbase + tid], sI[tid]);
}

__global__ __launch_bounds__(256) void k_gbB(
    const float* __restrict__ feat, const float* __restrict__ Isum,
    float* __restrict__ Bv, float* __restrict__ cB, float* __restrict__ gB,
    float* __restrict__ egb)
{
    int i = blockIdx.x*256 + threadIdx.x;
    if (i >= NATOMS) return;
    float q   = feat[7*i+0];
    float rad = feat[7*i+1];
    float rho = rad - OFFSETC;
    float psi = Isum[i]*rho;
    float u = psi*(ALPHAC + psi*(-BETAC + GAMMAC*psi));
    float t = tanhf(u);
    float B = 1.0f/(1.0f/rho - t/rad);
    Bv[i] = B;
    float du = ALPHAC + psi*(-2.0f*BETAC + 3.0f*GAMMAC*psi);
    cB[i] = B*B*((1.0f-t*t)/rad)*du*rho;
    float Cs = 0.5f*PREFC*q*q;
    egb[i] = Cs/B;
    gB[i]  = -Cs/(B*B);
}

__global__ __launch_bounds__(256) void k_gbC(
    const float* __restrict__ pos, const float* __restrict__ feat,
    const int* __restrict__ ei, const float* __restrict__ Bv,
    float* __restrict__ egb, float* __restrict__ gdgb, float* __restrict__ gB)
{
    __shared__ float sE[256], sG[256];
    int tid = threadIdx.x;
    sE[tid]=0.f; sG[tid]=0.f;
    __syncthreads();
    int T = blockIdx.x*256 + tid;
    int s = T >> 3, p = T & 7;
    int e0 = s*32 + p*4;
    int mbase = (blockIdx.x >> 3) * 256;
    float px = pos[3*s+0], py = pos[3*s+1], pz = pos[3*s+2];
    float qs = feat[7*s+0];
    float Bs = Bv[s];
    float gsrc = 0.f;
    const int* dP = ei + EGB;
#pragma unroll
    for (int j=0;j<4;j++){
        int dd = dP[e0+j];
        float dx = px - pos[3*dd+0];
        float dy = py - pos[3*dd+1];
        float dz = pz - pos[3*dd+2];
        float d2 = dx*dx+dy*dy+dz*dz + 1e-12f;
        float d  = sqrtf(d2);
        float Bd = Bv[dd];
        float C = 0.5f*PREFC*feat[7*dd+0]*qs;
        float P = Bd*Bs;
        float ex = __expf(-d2/(4.f*P));
        float f2 = d2 + P*ex;
        float f  = sqrtf(f2);
        float f3i = 1.f/(f2*f);
        gdgb[e0+j] = -C*d*(1.f - 0.25f*ex)*f3i;
        float common = -C*ex*(1.f + d2/(4.f*P))*0.5f*f3i;
        atomicAdd(&sE[dd & 255], C/f);
        atomicAdd(&sG[dd & 255], common*Bs);
        gsrc += common*Bd;
    }
    gsrc += __shfl_xor(gsrc,1);
    gsrc += __shfl_xor(gsrc,2);
    gsrc += __shfl_xor(gsrc,4);
    if (p==0) atomicAdd(&sG[s & 255], gsrc);
    __syncthreads();
    atomicAdd(&egb[mbase + tid], sE[tid]);
    atomicAdd(&gB[mbase + tid],  sG[tid]);
}

__global__ __launch_bounds__(256) void k_gbD(
    const float* __restrict__ gB, float* __restrict__ cB)
{
    int i = blockIdx.x*256 + threadIdx.x;
    if (i < NATOMS) cB[i] *= gB[i];
}

__global__ __launch_bounds__(256) void k_gbE(
    const float* __restrict__ pos, const float* __restrict__ feat,
    const int* __restrict__ ei, const float* __restrict__ cBg,
    const float* __restrict__ gdgb, float* __restrict__ grad)
{
    __shared__ float sGx[256], sGy[256], sGz[256];
    int tid = threadIdx.x;
    sGx[tid]=0.f; sGy[tid]=0.f; sGz[tid]=0.f;
    __syncthreads();
    int T = blockIdx.x*256 + tid;
    int s = T >> 3, p = T & 7;
    int e0 = s*32 + p*4;
    int mbase = (blockIdx.x >> 3) * 256;
    float px = pos[3*s+0], py = pos[3*s+1], pz = pos[3*s+2];
    float sr = feat[7*s+2] * (feat[7*s+1] - OFFSETC);
    float gx=0.f, gy=0.f, gz=0.f;
    const int* dP = ei + EGB;
#pragma unroll
    for (int j=0;j<4;j++){
        int dd = dP[e0+j];
        float dx = px - pos[3*dd+0];
        float dy = py - pos[3*dd+1];
        float dz = pz - pos[3*dd+2];
        float d2 = dx*dx+dy*dy+dz*dz + 1e-12f;
        float d  = sqrtf(d2);
        float rho_i = feat[7*dd+1] - OFFSETC;
        float U = d + sr;
        float gd = gdgb[e0+j];
        if (rho_i < U){
            float aa = fabsf(d - sr);
            float L, Lp;
            if (rho_i >= aa){ L = rho_i; Lp = 0.f; }
            else { L = aa; Lp = (d >= sr) ? 1.f : -1.f; }
            float invU = 1.f/U, invL = 1.f/L;
            float invU2=invU*invU, invL2=invL*invL;
            float dIdd = -0.5f*Lp*invL2 + 0.5f*invU2
                + 0.125f*(1.f + sr*sr/d2)*(invU2 - invL2)
                + 0.125f*(d - sr*sr/d)*(2.f*Lp*invL2*invL - 2.f*invU2*invU)
                + 0.25f*((Lp*invL - invU)/d - __logf(L*invU)/d2);
            gd += cBg[dd]*dIdd;
        }
        float c = gd/d;
        gx += c*dx; gy += c*dy; gz += c*dz;
        int dl = dd & 255;
        atomicAdd(&sGx[dl], -c*dx);
        atomicAdd(&sGy[dl], -c*dy);
        atomicAdd(&sGz[dl], -c*dz);
    }
    gx += __shfl_xor(gx,1); gx += __shfl_xor(gx,2); gx += __shfl_xor(gx,4);
    gy += __shfl_xor(gy,1); gy += __shfl_xor(gy,2); gy += __shfl_xor(gy,4);
    gz += __shfl_xor(gz,1); gz += __shfl_xor(gz,2); gz += __shfl_xor(gz,4);
    if (p==0){
        int sl = s & 255;
        atomicAdd(&sGx[sl], gx);
        atomicAdd(&sGy[sl], gy);
        atomicAdd(&sGz[sl], gz);
    }
    __syncthreads();
    int i = mbase + tid;
    atomicAdd(&grad[3*i+0], sGx[tid]);
    atomicAdd(&grad[3*i+1], sGy[tid]);
    atomicAdd(&grad[3*i+2], sGz[tid]);
}

// ---------------- GNN: dist + CSR build ----------------
__global__ __launch_bounds__(256) void k_dist(
    const float* __restrict__ pos, const int* __restrict__ gei,
    float* __restrict__ dgnn, int* __restrict__ cnt)
{
    int e = blockIdx.x*256 + threadIdx.x;
    if (e >= EGNN) return;
    int s = gei[e], dd = gei[EGNN+e];
    float dx = pos[3*s+0] - pos[3*dd+0];
    float dy = pos[3*s+1] - pos[3*dd+1];
    float dz = pos[3*s+2] - pos[3*dd+2];
    dgnn[e] = sqrtf(dx*dx+dy*dy+dz*dz + 1e-12f);
    atomicAdd(&cnt[dd], 1);
}

__global__ __launch_bounds__(256) void k_scan(
    const int* __restrict__ cnt, int* __restrict__ rptr, int* __restrict__ cursor)
{
    __shared__ int sc[256];
    int m = blockIdx.x, t = threadIdx.x;
    int c = cnt[m*256+t];
    sc[t] = c; __syncthreads();
    for (int off=1; off<256; off<<=1){
        int x = (t>=off) ? sc[t-off] : 0;
        __syncthreads();
        sc[t] += x;
        __syncthreads();
    }
    int ex = m*4096 + sc[t] - c;
    rptr[m*256+t] = ex;
    cursor[m*256+t] = ex;
}

__global__ __launch_bounds__(256) void k_fill(
    const int* __restrict__ gei, int* __restrict__ cursor, int* __restrict__ csr)
{
    int e = blockIdx.x*256 + threadIdx.x;
    if (e >= EGNN) return;
    int dst = gei[EGNN+e];
    int pos = atomicAdd(&cursor[dst], 1);
    csr[pos] = e;
}

// ---------------- weight prep ----------------
__global__ __launch_bounds__(256) void k_wprep(
    const float* __restrict__ A2, const float* __restrict__ C1,
    const float* __restrict__ A3, const float* __restrict__ C2,
    short* __restrict__ C1t, short* __restrict__ C2t,
    short* __restrict__ A2at, short* __restrict__ A2bt,
    short* __restrict__ A3at, short* __restrict__ A3bt,
    short* __restrict__ rA2a, short* __restrict__ rA2b,
    short* __restrict__ rA3a, short* __restrict__ rA3b,
    short* __restrict__ rC1, short* __restrict__ rC2)
{
    int gid = blockIdx.x*256 + threadIdx.x;
    int j = gid >> 7, k = gid & 127;
    C1t[gid]  = f2s(C1[k*HID+j]);
    C2t[gid]  = f2s(C2[k*HID+j]);
    A2at[gid] = f2s(A2[k*HID+j]);
    A2bt[gid] = f2s(A2[(HID+k)*HID+j]);
    A3at[gid] = f2s(A3[k*HID+j]);
    A3bt[gid] = f2s(A3[(HID+k)*HID+j]);
    rA2a[gid] = f2s(A2[gid]);
    rA2b[gid] = f2s(A2[HID*HID+gid]);
    rA3a[gid] = f2s(A3[gid]);
    rA3b[gid] = f2s(A3[HID*HID+gid]);
    rC1[gid]  = f2s(C1[gid]);
    rC2[gid]  = f2s(C2[gid]);
}

// ---------------- GNN compute ----------------
__global__ __launch_bounds__(256) void k_uv1(
    const float* __restrict__ feat, const float* __restrict__ A1,
    bf* __restrict__ u1, bf* __restrict__ v1)
{
    int gid = blockIdx.x*256 + threadIdx.x;
    int i = gid >> 7, k = gid & 127;
    float q = feat[7*i+0], r = feat[7*i+1];
    u1[gid] = f2b(q*A1[k]       + r*A1[HID+k]);
    v1[gid] = f2b(q*A1[2*HID+k] + r*A1[3*HID+k]);
}

__global__ __launch_bounds__(128) void k_edge_fwd_dst(
    const int* __restrict__ csr, const int* __restrict__ rptr, const int* __restrict__ cnt,
    const float* __restrict__ dgnn, const bf* __restrict__ u, const bf* __restrict__ v,
    const float* __restrict__ wdp, const float* __restrict__ bb,
    float* __restrict__ Hs)
{
    __shared__ int ss[128]; __shared__ float sd[128];
    int dst = blockIdx.x, k = threadIdx.x;
    int n = cnt[dst], r0 = rptr[dst];
    if (k < n){ int e = csr[r0+k]; ss[k] = e>>4; sd[k] = dgnn[e]; }
    __syncthreads();
    float vk = b2f(v[dst*HID+k]), wd = wdp[k], bk = bb[k];
    float hsum = 0.f;
    for (int j=0;j<n;j++){
        float a = b2f(u[ss[j]*HID+k]) + vk + sd[j]*wd + bk;
        hsum += a*sigf(a);
    }
    Hs[dst*HID+k] = hsum;
}

__global__ __launch_bounds__(256) void k_node_fwd_uv_mfma(
    const float* __restrict__ Hs, const int* __restrict__ cnt,
    const short* __restrict__ Ct, const float* __restrict__ D,
    const short* __restrict__ Aat, const short* __restrict__ Abt,
    float* __restrict__ z, bf* __restrict__ u, bf* __restrict__ v)
{
    __shared__ short sx[64*HID];
    int lane = threadIdx.x & 63, w = threadIdx.x >> 6;
    int m0 = blockIdx.x*64 + w*16;
    int ar = lane & 15, kg = lane >> 4;
    bf8v af[4];
#pragma unroll
    for (int s=0;s<4;s++) af[s] = pack8(Hs + (size_t)(m0+ar)*HID + s*32 + kg*8);
    f4v acc[8];
#pragma unroll
    for (int nt=0;nt<8;nt++){
        acc[nt] = (f4v){0.f,0.f,0.f,0.f};
        const short* bp = Ct + (nt*16+ar)*HID + kg*8;
#pragma unroll
        for (int s=0;s<4;s++){
            bf8v bv = *(const bf8v*)(bp + s*32);
            acc[nt] = __builtin_amdgcn_mfma_f32_16x16x32_bf16(af[s], bv, acc[nt], 0,0,0);
        }
    }
    float cn[4];
#pragma unroll
    for (int r=0;r<4;r++) cn[r] = (float)cnt[m0 + kg*4 + r];
#pragma unroll
    for (int nt=0;nt<8;nt++){
        int j = nt*16 + ar;
        float Dj = D[j];
#pragma unroll
        for (int r=0;r<4;r++){
            int m = m0 + kg*4 + r;
            float zv = acc[nt][r] + cn[r]*Dj;
            z[(size_t)m*HID + j] = zv;
            float xv = zv*sigf(zv);
            sx[(w*16 + kg*4 + r)*HID + j] = f2s(xv);
        }
    }
    __syncthreads();
#pragma unroll
    for (int s=0;s<4;s++) af[s] = *(const bf8v*)&sx[(w*16+ar)*HID + s*32 + kg*8];
    f4v au[8], av[8];
#pragma unroll
    for (int nt=0;nt<8;nt++){
        au[nt] = (f4v){0.f,0.f,0.f,0.f};
        av[nt] = (f4v){0.f,0.f,0.f,0.f};
        const short* bpa = Aat + (nt*16+ar)*HID + kg*8;
        const short* bpb = Abt + (nt*16+ar)*HID + kg*8;
#pragma unroll
        for (int s=0;s<4;s++){
            bf8v ba = *(const bf8v*)(bpa + s*32);
            bf8v bb = *(const bf8v*)(bpb + s*32);
            au[nt] = __builtin_amdgcn_mfma_f32_16x16x32_bf16(af[s], ba, au[nt], 0,0,0);
            av[nt] = __builtin_amdgcn_mfma_f32_16x16x32_bf16(af[s], bb, av[nt], 0,0,0);
        }
    }
#pragma unroll
    for (int nt=0;nt<8;nt++){
        int j = nt*16 + ar;
#pragma unroll
        for (int r=0;r<4;r++){
            int m = m0 + kg*4 + r;
            u[(size_t)m*HID + j] = f2b(au[nt][r]);
            v[(size_t)m*HID + j] = f2b(av[nt][r]);
        }
    }
}

__global__ __launch_bounds__(256) void k_gx_node_bwd_mfma(
    const float* __restrict__ Gs, const float* __restrict__ Gd,
    const short* __restrict__ Ra, const short* __restrict__ Rb,
    const float* __restrict__ z, const short* __restrict__ Rc,
    bf* __restrict__ gH)
{
    __shared__ short st[64*HID];
    int lane = threadIdx.x & 63, w = threadIdx.x >> 6;
    int m0 = blockIdx.x*64 + w*16;
    int ar = lane & 15, kg = lane >> 4;
    bf8v as_[4], ad_[4];
#pragma unroll
    for (int s=0;s<4;s++){
        as_[s] = pack8(Gs + (size_t)(m0+ar)*HID + s*32 + kg*8);
        ad_[s] = pack8(Gd + (size_t)(m0+ar)*HID + s*32 + kg*8);
    }
    f4v acc[8];
#pragma unroll
    for (int nt=0;nt<8;nt++){
        acc[nt] = (f4v){0.f,0.f,0.f,0.f};
        const short* bpa = Ra + (nt*16+ar)*HID + kg*8;
        const short* bpb = Rb + (nt*16+ar)*HID + kg*8;
#pragma unroll
        for (int s=0;s<4;s++){
            bf8v ba = *(const bf8v*)(bpa + s*32);
            bf8v bb = *(const bf8v*)(bpb + s*32);
            acc[nt] = __builtin_amdgcn_mfma_f32_16x16x32_bf16(as_[s], ba, acc[nt], 0,0,0);
            acc[nt] = __builtin_amdgcn_mfma_f32_16x16x32_bf16(ad_[s], bb, acc[nt], 0,0,0);
        }
    }
#pragma unroll
    for (int nt=0;nt<8;nt++){
        int j = nt*16 + ar;
#pragma unroll
        for (int r=0;r<4;r++){
            int m = m0 + kg*4 + r;
            float zz = z[(size_t)m*HID + j];
            float sg = sigf(zz);
            float t = acc[nt][r]*sg*(1.f + zz*(1.f - sg));
            st[(w*16 + kg*4 + r)*HID + j] = f2s(t);
        }
    }
    __syncthreads();
    bf8v af[4];
#pragma unroll
    for (int s=0;s<4;s++) af[s] = *(const bf8v*)&st[(w*16+ar)*HID + s*32 + kg*8];
    f4v a2[8];
#pragma unroll
    for (int nt=0;nt<8;nt++){
        a2[nt] = (f4v){0.f,0.f,0.f,0.f};
        const short* bp = Rc + (nt*16+ar)*HID + kg*8;
#pragma unroll
        for (int s=0;s<4;s++){
            bf8v bc = *(const bf8v*)(bp + s*32);
            a2[nt] = __builtin_amdgcn_mfma_f32_16x16x32_bf16(af[s], bc, a2[nt], 0,0,0);
        }
    }
#pragma unroll
    for (int nt=0;nt<8;nt++){
        int j = nt*16 + ar;
#pragma unroll
        for (int r=0;r<4;r++){
            gH[(size_t)(m0 + kg*4 + r)*HID + j] = f2b(a2[nt][r]);
        }
    }
}

// merged layer-3 src+dst passes (grid 2*NATOMS)
__global__ __launch_bounds__(128) void k_l3(
    const int* __restrict__ gei,
    const int* __restrict__ csr, const int* __restrict__ rptr, const int* __restrict__ cnt,
    const float* __restrict__ dgnn, const bf* __restrict__ u, const bf* __restrict__ v,
    const float* __restrict__ A3, const float* __restrict__ B3,
    const float* __restrict__ C3, const float* __restrict__ D3,
    float* __restrict__ Gs, float* __restrict__ Gd, float* __restrict__ x3,
    float* __restrict__ gdg)
{
    int k = threadIdx.x;
    if (blockIdx.x < NATOMS){
        __shared__ float sQ[16][130];
        int s = blockIdx.x;
        float uk = b2f(u[s*HID+k]), wd = A3[256*HID+k], bk = B3[k], ck = C3[k];
        int e0 = s*16;
        int dsts[16]; float dv[16];
#pragma unroll
        for (int t=0;t<16;t++){ dsts[t]=gei[EGNN+e0+t]; dv[t]=dgnn[e0+t]; }
        float gs = 0.f;
#pragma unroll 4
        for (int t=0;t<16;t++){
            float a = uk + b2f(v[dsts[t]*HID+k]) + dv[t]*wd + bk;
            float sg = sigf(a);
            float ds = sg*(1.f + a*(1.f - sg));
            float ga = ck*ds;
            gs += ga;
            sQ[t][k] = ga*wd;
        }
        Gs[s*HID+k] = gs;
        __syncthreads();
        int t = k >> 3, r = k & 7;
        float pg = 0.f;
#pragma unroll
        for (int i=0;i<16;i++) pg += sQ[t][i + 16*r];
        pg += __shfl_xor(pg,1); pg += __shfl_xor(pg,2); pg += __shfl_xor(pg,4);
        if (r==0) gdg[e0+t] = pg;
    } else {
        __shared__ int ss[128]; __shared__ float sd[128]; __shared__ float rr[2];
        int dst = blockIdx.x - NATOMS;
        int n = cnt[dst], r0 = rptr[dst];
        if (k < n){ int e = csr[r0+k]; ss[k] = e>>4; sd[k] = dgnn[e]; }
        __syncthreads();
        float vk = b2f(v[dst*HID+k]), wd = A3[256*HID+k], bk = B3[k], ck = C3[k];
        float hsum = 0.f, dssum = 0.f;
        for (int j=0;j<n;j++){
            float a = b2f(u[ss[j]*HID+k]) + vk + sd[j]*wd + bk;
            float sg = sigf(a);
            hsum += a*sg;
            dssum += sg*(1.f + a*(1.f - sg));
        }
        Gd[dst*HID+k] = ck*dssum;
        float pv = waveRed(ck*hsum);
        if ((k&63)==0) rr[k>>6] = pv;
        __syncthreads();
        if (k==0) x3[dst] = rr[0] + rr[1] + (float)n*D3[0];
    }
}

// merged layer-2 bwd src+dst passes (grid 2*NATOMS)
__global__ __launch_bounds__(128) void k_bwd(
    const int* __restrict__ gei,
    const int* __restrict__ csr, const int* __restrict__ rptr, const int* __restrict__ cnt,
    const float* __restrict__ dgnn, const bf* __restrict__ u, const bf* __restrict__ v,
    const float* __restrict__ wdp, const float* __restrict__ bb,
    const bf* __restrict__ gH,
    float* __restrict__ Gs, float* __restrict__ Gd, float* __restrict__ gdg)
{
    int k = threadIdx.x;
    if (blockIdx.x < NATOMS){
        __shared__ float sQ[16][130];
        int s = blockIdx.x;
        float uk = b2f(u[s*HID+k]), wd = wdp[k], bk = bb[k];
        int e0 = s*16;
        int dsts[16]; float dv[16];
#pragma unroll
        for (int t=0;t<16;t++){ dsts[t]=gei[EGNN+e0+t]; dv[t]=dgnn[e0+t]; }
        float gs = 0.f;
#pragma unroll 4
        for (int t=0;t<16;t++){
            float a = uk + b2f(v[dsts[t]*HID+k]) + dv[t]*wd + bk;
            float sg = sigf(a);
            float ds = sg*(1.f + a*(1.f - sg));
            float ga = b2f(gH[dsts[t]*HID+k])*ds;
            gs += ga;
            sQ[t][k] = ga*wd;
        }
        Gs[s*HID+k] = gs;
        __syncthreads();
        int t = k >> 3, r = k & 7;
        float pg = 0.f;
#pragma unroll
        for (int i=0;i<16;i++) pg += sQ[t][i + 16*r];
        pg += __shfl_xor(pg,1); pg += __shfl_xor(pg,2); pg += __shfl_xor(pg,4);
        if (r==0) gdg[e0+t] += pg;
    } else {
        __shared__ int ss[128]; __shared__ float sd[128];
        int dst = blockIdx.x - NATOMS;
        int n = cnt[dst], r0 = rptr[dst];
        if (k < n){ int e = csr[r0+k]; ss[k] = e>>4; sd[k] = dgnn[e]; }
        __syncthreads();
        float vk = b2f(v[dst*HID+k]), wd = wdp[k], bk = bb[k];
        float dssum = 0.f;
        for (int j=0;j<n;j++){
            float a = b2f(u[ss[j]*HID+k]) + vk + sd[j]*wd + bk;
            float sg = sigf(a);
            dssum += sg*(1.f + a*(1.f - sg));
        }
        Gd[dst*HID+k] = b2f(gH[dst*HID+k])*dssum;
    }
}

__global__ __launch_bounds__(128) void k_bwd1_src(
    const int* __restrict__ gei, const float* __restrict__ dgnn,
    const bf* __restrict__ u, const bf* __restrict__ v,
    const float* __restrict__ wdp, const float* __restrict__ bb,
    const bf* __restrict__ gH, float* __restrict__ gdg)
{
    __shared__ float sQ[16][130];
    int s = blockIdx.x, k = threadIdx.x;
    float uk = b2f(u[s*HID+k]), wd = wdp[k], bk = bb[k];
    int e0 = s*16;
    int dsts[16]; float dv[16];
#pragma unroll
    for (int t=0;t<16;t++){ dsts[t]=gei[EGNN+e0+t]; dv[t]=dgnn[e0+t]; }
#pragma unroll 4
    for (int t=0;t<16;t++){
        float a = uk + b2f(v[dsts[t]*HID+k]) + dv[t]*wd + bk;
        float sg = sigf(a);
        float ds = sg*(1.f + a*(1.f - sg));
        float ga = b2f(gH[dsts[t]*HID+k])*ds;
        sQ[t][k] = ga*wd;
    }
    __syncthreads();
    int t = k >> 3, r = k & 7;
    float pg = 0.f;
#pragma unroll
    for (int i=0;i<16;i++) pg += sQ[t][i + 16*r];
    pg += __shfl_xor(pg,1); pg += __shfl_xor(pg,2); pg += __shfl_xor(pg,4);
    if (r==0) gdg[e0+t] += pg;
}

__global__ __launch_bounds__(256) void k_force_atom(
    const float* __restrict__ pos, const int* __restrict__ gei,
    const int* __restrict__ csr, const int* __restrict__ rptr, const int* __restrict__ cnt,
    const float* __restrict__ dgnn, const float* __restrict__ gdg,
    float* __restrict__ grad)
{
    int T = blockIdx.x*256 + threadIdx.x;
    int i = T >> 3, p = T & 7;
    float px = pos[3*i+0], py = pos[3*i+1], pz = pos[3*i+2];
    float ax=0.f, ay=0.f, az=0.f;
    for (int j=p;j<16;j+=8){
        int e = i*16 + j;
        int o = gei[EGNN+e];
        float c = gdg[e]/dgnn[e];
        ax += c*(px - pos[3*o+0]);
        ay += c*(py - pos[3*o+1]);
        az += c*(pz - pos[3*o+2]);
    }
    int n = cnt[i], r0 = rptr[i];
    for (int j=p;j<n;j+=8){
        int e = csr[r0+j];
        int o = e >> 4;
        float c = gdg[e]/dgnn[e];
        ax += c*(px - pos[3*o+0]);
        ay += c*(py - pos[3*o+1]);
        az += c*(pz - pos[3*o+2]);
    }
    ax += __shfl_xor(ax,1); ax += __shfl_xor(ax,2); ax += __shfl_xor(ax,4);
    ay += __shfl_xor(ay,1); ay += __shfl_xor(ay,2); ay += __shfl_xor(ay,4);
    az += __shfl_xor(az,1); az += __shfl_xor(az,2); az += __shfl_xor(az,4);
    if (p==0){
        grad[3*i+0] += ax;
        grad[3*i+1] += ay;
        grad[3*i+2] += az;
    }
}

__global__ __launch_bounds__(256) void k_final(
    const float* __restrict__ egb, const float* __restrict__ x3,
    const float* __restrict__ grad, float* __restrict__ out)
{
    __shared__ float red[4];
    int m = blockIdx.x, tid = threadIdx.x;
    int i = m*ATOMSM + tid;
    float en = egb[i] + x3[i];
    float v = waveRed(en);
    int wave = tid>>6, lane = tid&63;
    if (lane==0) red[wave] = v;
    __syncthreads();
    if (tid==0) out[m] = red[0]+red[1]+red[2]+red[3];
    float* f = out + MOLS;
    f[3*i+0] = -grad[3*i+0];
    f[3*i+1] = -grad[3*i+1];
    f[3*i+2] = -grad[3*i+2];
}

extern "C" void kernel_launch(void* const* d_in, const int* in_sizes, int n_in,
                              void* d_out, int out_size, void* d_ws, size_t ws_size,
                              hipStream_t stream)
{
    const float* pos  = (const float*)d_in[0];
    const float* feat = (const float*)d_in[1];
    const int* ei  = (const int*)d_in[3];
    const int* gei = (const int*)d_in[4];
    const float* A1f = (const float*)d_in[5];  const float* B1f = (const float*)d_in[6];
    const float* C1f = (const float*)d_in[7];  const float* D1f = (const float*)d_in[8];
    const float* A2f = (const float*)d_in[9];  const float* B2f = (const float*)d_in[10];
    const float* C2f = (const float*)d_in[11]; const float* D2f = (const float*)d_in[12];
    const float* A3f = (const float*)d_in[13]; const float* B3f = (const float*)d_in[14];
    const float* C3f = (const float*)d_in[15]; const float* D3f = (const float*)d_in[16];

    float* w = (float*)d_ws;
    size_t off = 0;
    auto nxt = [&](size_t n)->float*{ float* p = w + off; off += (n + 255) & ~(size_t)255; return p; };
    float* Isum = nxt(NATOMS); float* Bv = nxt(NATOMS); float* cB = nxt(NATOMS);
    float* gB = nxt(NATOMS); float* egb = nxt(NATOMS); float* x3 = nxt(NATOMS);
    int*   cnt  = (int*)nxt(NATOMS);
    int*   rptr = (int*)nxt(NATOMS);
    int*   curs = (int*)nxt(NATOMS);
    int*   csr  = (int*)nxt(EGNN);
    float* dgnn = nxt(EGNN); float* gdgnn = nxt(EGNN); float* gdgb = nxt(EGB);
    float* grad = nxt(3*NATOMS);
    float* z1 = nxt(NH); float* z2 = nxt(NH);
    float* Hs1 = nxt(NH); float* Hs2 = nxt(NH);
    float* Gs3 = nxt(NH); float* Gd3 = nxt(NH);
    bf* u1 = (bf*)nxt(NH/2); bf* v1 = (bf*)nxt(NH/2);
    bf* u2 = (bf*)nxt(NH/2); bf* v2 = (bf*)nxt(NH/2);
    bf* v3 = (bf*)nxt(NH/2);
    short* C1t  = (short*)nxt(8192); short* C2t  = (short*)nxt(8192);
    short* A2at = (short*)nxt(8192); short* A2bt = (short*)nxt(8192);
    short* A3at = (short*)nxt(8192); short* A3bt = (short*)nxt(8192);
    short* rA2a = (short*)nxt(8192); short* rA2b = (short*)nxt(8192);
    short* rA3a = (short*)nxt(8192); short* rA3b = (short*)nxt(8192);
    short* rC1  = (short*)nxt(8192); short* rC2  = (short*)nxt(8192);
    bf* u3  = (bf*)Hs1;
    bf* gH2 = (bf*)Hs2;
    float* Gs2 = Gs3;
    float* Gd2 = Gd3;
    bf* gH1 = u3;

    hipMemsetAsync(Isum, 0, NATOMS*sizeof(float), stream);
    hipMemsetAsync(cnt,  0, NATOMS*sizeof(int), stream);
    hipMemsetAsync(grad, 0, 3*NATOMS*sizeof(float), stream);

    k_wprep<<<64,256,0,stream>>>(A2f, C1f, A3f, C2f,
        C1t, C2t, A2at, A2bt, A3at, A3bt, rA2a, rA2b, rA3a, rA3b, rC1, rC2);

    // GB chain (LDS molecule-tile staged)
    k_gbA<<<512,256,0,stream>>>(pos, feat, ei, Isum);
    k_gbB<<<NATOMS/256,256,0,stream>>>(feat, Isum, Bv, cB, gB, egb);
    k_gbC<<<512,256,0,stream>>>(pos, feat, ei, Bv, egb, gdgb, gB);
    k_gbD<<<NATOMS/256,256,0,stream>>>(gB, cB);
    k_gbE<<<512,256,0,stream>>>(pos, feat, ei, cB, gdgb, grad);

    // dist + CSR build
    k_dist<<<EGNN/256,256,0,stream>>>(pos, gei, dgnn, cnt);
    k_scan<<<MOLS,256,0,stream>>>(cnt, rptr, curs);
    k_fill<<<EGNN/256,256,0,stream>>>(gei, curs, csr);

    // forward
    k_uv1<<<NH/256,256,0,stream>>>(feat, A1f, u1, v1);
    k_edge_fwd_dst<<<NATOMS,128,0,stream>>>(csr, rptr, cnt, dgnn, u1, v1, A1f+4*HID, B1f, Hs1);
    k_node_fwd_uv_mfma<<<NATOMS/64,256,0,stream>>>(Hs1, cnt, C1t, D1f, A2at, A2bt, z1, u2, v2);
    k_edge_fwd_dst<<<NATOMS,128,0,stream>>>(csr, rptr, cnt, dgnn, u2, v2, A2f+256*HID, B2f, Hs2);
    k_node_fwd_uv_mfma<<<NATOMS/64,256,0,stream>>>(Hs2, cnt, C2t, D2f, A3at, A3bt, z2, u3, v3);

    // layer-3 fwd+bwd (merged src/dst)
    k_l3<<<2*NATOMS,128,0,stream>>>(gei, csr, rptr, cnt, dgnn, u3, v3,
                                    A3f, B3f, C3f, D3f, Gs3, Gd3, x3, gdgnn);

    // backward chain
    k_gx_node_bwd_mfma<<<NATOMS/64,256,0,stream>>>(Gs3, Gd3, rA3a, rA3b, z2, rC2, gH2);
    k_bwd<<<2*NATOMS,128,0,stream>>>(gei, csr, rptr, cnt, dgnn, u2, v2,
                                     A2f+256*HID, B2f, gH2, Gs2, Gd2, gdgnn);
    k_gx_node_bwd_mfma<<<NATOMS/64,256,0,stream>>>(Gs2, Gd2, rA2a, rA2b, z1, rC1, gH1);
    k_bwd1_src<<<NATOMS,128,0,stream>>>(gei, dgnn, u1, v1, A1f+4*HID, B1f, gH1, gdgnn);
    k_force_atom<<<NATOMS*8/256,256,0,stream>>>(pos, gei, csr, rptr, cnt, dgnn, gdgnn, grad);

    k_final<<<MOLS,256,0,stream>>>(egb, x3, grad, (float*)d_out);
}